// Round 2
// baseline (838.592 us; speedup 1.0000x reference)
//
#include <hip/hip_runtime.h>
#include <hip/hip_bf16.h>

// GCN 2-layer: N=50000 nodes, E=800000 edges, 256 -> 64 (relu) -> 40 (log_softmax)
// Float inputs may be fp32 (reference dtype) or bf16 (harness variant); edge_index
// may be int32 or int64. We DETECT both on device each launch and branch uniformly.

constexpr int NN   = 50000;
constexpr int NE   = 800000;
constexpr int FEAT = 256;
constexpr int HID  = 64;
constexpr int OUTD = 40;

__device__ __forceinline__ float b2f(__hip_bfloat16 v) { return __bfloat162float(v); }
__device__ __forceinline__ float bflo(unsigned u) { return __uint_as_float(u << 16); }
__device__ __forceinline__ float bfhi(unsigned u) { return __uint_as_float(u & 0xffff0000u); }

__device__ __forceinline__ float loadF(const void* p, int i, bool f32) {
    return f32 ? ((const float*)p)[i] : b2f(((const __hip_bfloat16*)p)[i]);
}
// edge row: 0 = src, 1 = dst. int64 little-endian: value in low 32-bit word.
__device__ __forceinline__ int loadE(const int* ei, int e, int row, bool i64) {
    long long idx = (long long)row * NE + e;
    return i64 ? ei[2 * idx] : ei[idx];
}

// ---- dtype detection -------------------------------------------------------
// flags[0]: 1 if float arrays are fp32, 0 if bf16. flags[1]: 1 if edges int64.
__global__ void k_detect(const unsigned* __restrict__ xw, const int* __restrict__ ew,
                         int* flags) {
    if (threadIdx.x == 0 && blockIdx.x == 0) {
        int outliers = 0;
        for (int i = 0; i < 256; i++) {
            int e = (xw[i] >> 7) & 0xFF;   // exponent field of low bf16 half
            if (e < 100 || e > 140) outliers++;
        }
        flags[0] = (outliers > 64) ? 1 : 0;
        int nz = 0;
        for (int i = 1; i < 64; i += 2)
            if (ew[i] != 0) nz++;
        flags[1] = (nz == 0) ? 1 : 0;
    }
}

// ---- degree / normalization ------------------------------------------------
__global__ __launch_bounds__(256) void k_deg_init(float* deg) {
    int i = blockIdx.x * 256 + threadIdx.x;
    if (i < NN) deg[i] = 1.0f;  // self loop
}
__global__ __launch_bounds__(256) void k_deg_acc(const int* __restrict__ ei,
                                                 const int* __restrict__ flags, float* deg) {
    const bool i64 = flags[1] != 0;
    int e = blockIdx.x * 256 + threadIdx.x;
    if (e < NE) atomicAdd(&deg[loadE(ei, e, 1, i64)], 1.0f);
}
__global__ __launch_bounds__(256) void k_rsqrt(float* deg) {
    int i = blockIdx.x * 256 + threadIdx.x;
    if (i < NN) deg[i] = rsqrtf(deg[i]);
}

// ---- layer 1 GEMM: h1 = x @ W1 ; agg1 = h1 * dinv^2 (self-loop term) -------
// wave per 8 rows, lane = output col (HID=64). W1^T in LDS as fp32, stride 260
// (260%32==4 -> b128 reads conflict-free).
__global__ __launch_bounds__(256) void k_gemm1(const void* __restrict__ xb,
                                               const void* __restrict__ W1,
                                               const float* __restrict__ dinv,
                                               const int* __restrict__ flags,
                                               float* __restrict__ h1,
                                               float* __restrict__ agg1) {
    __shared__ __align__(16) float w1t[64 * 260];
    const bool f32 = flags[0] != 0;
    int tid = threadIdx.x;
    for (int idx = tid; idx < FEAT * HID; idx += 256) {
        int k = idx >> 6, l = idx & 63;          // W1 is [FEAT][HID] row-major
        w1t[l * 260 + k] = loadF(W1, idx, f32);
    }
    __syncthreads();
    int wid = tid >> 6, lane = tid & 63;
    int r0 = (blockIdx.x * 4 + wid) * 8;
    float acc[8] = {0, 0, 0, 0, 0, 0, 0, 0};
    if (f32) {
        const float* xf = (const float*)xb;
        for (int kb = 0; kb < FEAT; kb += 4) {
            float4 wv = *(const float4*)(w1t + lane * 260 + kb);
#pragma unroll
            for (int ri = 0; ri < 8; ri++) {
                int r = r0 + ri;
                if (r < NN) {
                    float4 xv = *(const float4*)(xf + (size_t)r * FEAT + kb);
                    acc[ri] += xv.x * wv.x + xv.y * wv.y + xv.z * wv.z + xv.w * wv.w;
                }
            }
        }
    } else {
        const unsigned short* xu = (const unsigned short*)xb;
        for (int kb = 0; kb < FEAT; kb += 8) {
            float4 wa = *(const float4*)(w1t + lane * 260 + kb);
            float4 wb = *(const float4*)(w1t + lane * 260 + kb + 4);
#pragma unroll
            for (int ri = 0; ri < 8; ri++) {
                int r = r0 + ri;
                if (r < NN) {
                    uint4 xv = *(const uint4*)(xu + (size_t)r * FEAT + kb);
                    acc[ri] += bflo(xv.x) * wa.x + bfhi(xv.x) * wa.y +
                               bflo(xv.y) * wa.z + bfhi(xv.y) * wa.w +
                               bflo(xv.z) * wb.x + bfhi(xv.z) * wb.y +
                               bflo(xv.w) * wb.z + bfhi(xv.w) * wb.w;
                }
            }
        }
    }
#pragma unroll
    for (int ri = 0; ri < 8; ri++) {
        int r = r0 + ri;
        if (r < NN) {
            float d = dinv[r];
            h1[r * HID + lane]   = acc[ri];
            agg1[r * HID + lane] = acc[ri] * d * d;
        }
    }
}

// ---- scatter-add layer 1: agg1[dst] += h1[src] * dinv[s]*dinv[d] -----------
__global__ __launch_bounds__(256) void k_scatter1(const int* __restrict__ ei,
                                                  const float* __restrict__ dinv,
                                                  const int* __restrict__ flags,
                                                  const float* __restrict__ h1,
                                                  float* __restrict__ agg1) {
    const bool i64 = flags[1] != 0;
    int wid = threadIdx.x >> 6, lane = threadIdx.x & 63;
    int e0 = blockIdx.x * 16 + wid * 4;
#pragma unroll
    for (int i = 0; i < 4; i++) {
        int e = e0 + i;
        if (e < NE) {
            int s = loadE(ei, e, 0, i64), d = loadE(ei, e, 1, i64);
            float w = dinv[s] * dinv[d];
            atomicAdd(&agg1[d * HID + lane], h1[s * HID + lane] * w);
        }
    }
}

// ---- layer 2 GEMM: h2 = relu(agg1 + b1) @ W2 ; agg2 = h2 * dinv^2 ----------
__global__ __launch_bounds__(256) void k_gemm2(const float* __restrict__ agg1,
                                               const void* __restrict__ W2,
                                               const void* __restrict__ b1,
                                               const float* __restrict__ dinv,
                                               const int* __restrict__ flags,
                                               float* __restrict__ h2,
                                               float* __restrict__ agg2) {
    __shared__ __align__(16) float w2t[40 * 68];  // [out col][k], stride 68
    __shared__ __align__(16) float b1s[64];
    const bool f32 = flags[0] != 0;
    int tid = threadIdx.x;
    for (int idx = tid; idx < HID * OUTD; idx += 256) {
        int k = idx / OUTD, l = idx % OUTD;      // W2 is [HID][OUTD] row-major
        w2t[l * 68 + k] = loadF(W2, idx, f32);
    }
    if (tid < HID) b1s[tid] = loadF(b1, tid, f32);
    __syncthreads();
    int wid = tid >> 6, lane = tid & 63;
    int lc = lane < OUTD ? lane : OUTD - 1;      // clamp: stay in-bounds, result unused
    int r0 = (blockIdx.x * 4 + wid) * 8;
    float acc[8] = {0, 0, 0, 0, 0, 0, 0, 0};
    for (int kb = 0; kb < HID; kb += 4) {
        float4 wv = *(const float4*)(w2t + lc * 68 + kb);
        float4 bv = *(const float4*)(b1s + kb);
#pragma unroll
        for (int ri = 0; ri < 8; ri++) {
            int r = r0 + ri;
            if (r < NN) {
                float4 av = *(const float4*)(agg1 + (size_t)r * HID + kb);
                float g0 = fmaxf(av.x + bv.x, 0.f);
                float g1 = fmaxf(av.y + bv.y, 0.f);
                float g2 = fmaxf(av.z + bv.z, 0.f);
                float g3 = fmaxf(av.w + bv.w, 0.f);
                acc[ri] += g0 * wv.x + g1 * wv.y + g2 * wv.z + g3 * wv.w;
            }
        }
    }
    if (lane < OUTD) {
#pragma unroll
        for (int ri = 0; ri < 8; ri++) {
            int r = r0 + ri;
            if (r < NN) {
                float d = dinv[r];
                h2[r * OUTD + lane]   = acc[ri];
                agg2[r * OUTD + lane] = acc[ri] * d * d;
            }
        }
    }
}

// ---- scatter-add layer 2 ---------------------------------------------------
__global__ __launch_bounds__(256) void k_scatter2(const int* __restrict__ ei,
                                                  const float* __restrict__ dinv,
                                                  const int* __restrict__ flags,
                                                  const float* __restrict__ h2,
                                                  float* __restrict__ agg2) {
    const bool i64 = flags[1] != 0;
    int wid = threadIdx.x >> 6, lane = threadIdx.x & 63;
    int e0 = blockIdx.x * 16 + wid * 4;
#pragma unroll
    for (int i = 0; i < 4; i++) {
        int e = e0 + i;
        if (e < NE) {
            int s = loadE(ei, e, 0, i64), d = loadE(ei, e, 1, i64);
            float w = dinv[s] * dinv[d];
            if (lane < OUTD)
                atomicAdd(&agg2[d * OUTD + lane], h2[s * OUTD + lane] * w);
        }
    }
}

// ---- bias + log_softmax (output dtype follows detected float dtype) --------
__global__ __launch_bounds__(256) void k_lsm(const float* __restrict__ agg2,
                                             const void* __restrict__ b2,
                                             const int* __restrict__ flags,
                                             void* __restrict__ out) {
    const bool f32 = flags[0] != 0;
    int n = blockIdx.x * 4 + (threadIdx.x >> 6);
    if (n >= NN) return;
    int lane = threadIdx.x & 63;
    float v = -3.0e38f;
    if (lane < OUTD) v = agg2[(size_t)n * OUTD + lane] + loadF(b2, lane, f32);
    float m = v;
#pragma unroll
    for (int off = 32; off; off >>= 1) m = fmaxf(m, __shfl_xor(m, off, 64));
    float ev = (lane < OUTD) ? expf(v - m) : 0.f;
    float s = ev;
#pragma unroll
    for (int off = 32; off; off >>= 1) s += __shfl_xor(s, off, 64);
    float lg = logf(s);
    if (lane < OUTD) {
        float r = v - m - lg;
        if (f32) ((float*)out)[(size_t)n * OUTD + lane] = r;
        else ((__hip_bfloat16*)out)[(size_t)n * OUTD + lane] = __float2bfloat16(r);
    }
}

extern "C" void kernel_launch(void* const* d_in, const int* in_sizes, int n_in,
                              void* d_out, int out_size, void* d_ws, size_t ws_size,
                              hipStream_t stream) {
    const void* x  = d_in[0];
    const int*  ei = (const int*)d_in[1];
    const void* W1 = d_in[2];
    const void* b1 = d_in[3];
    const void* W2 = d_in[4];
    const void* b2 = d_in[5];

    // ws layout (fp32 units): flags[16] | dinv[50048] | A[NN*64] (h1, then h2) |
    //                         agg1[NN*64] | agg2[NN*40]   -> 33.8 MB total
    float* ws   = (float*)d_ws;
    int*   flags = (int*)ws;
    float* dinv = ws + 16;
    float* A    = dinv + 50048;          // h1 [NN*HID]; reused as h2 [NN*OUTD]
    float* agg1 = A + (size_t)NN * HID;
    float* agg2 = agg1 + (size_t)NN * HID;
    float* h1 = A;
    float* h2 = A;

    k_detect<<<1, 64, 0, stream>>>((const unsigned*)x, ei, flags);
    k_deg_init<<<(NN + 255) / 256, 256, 0, stream>>>(dinv);
    k_deg_acc<<<(NE + 255) / 256, 256, 0, stream>>>(ei, flags, dinv);
    k_rsqrt<<<(NN + 255) / 256, 256, 0, stream>>>(dinv);
    k_gemm1<<<(NN + 31) / 32, 256, 0, stream>>>(x, W1, dinv, flags, h1, agg1);
    k_scatter1<<<(NE + 15) / 16, 256, 0, stream>>>(ei, dinv, flags, h1, agg1);
    k_gemm2<<<(NN + 31) / 32, 256, 0, stream>>>(agg1, W2, b1, dinv, flags, h2, agg2);
    k_scatter2<<<(NE + 15) / 16, 256, 0, stream>>>(ei, dinv, flags, h2, agg2);
    k_lsm<<<(NN + 3) / 4, 256, 0, stream>>>(agg2, b2, flags, (void*)d_out);
}

// Round 3
// 353.546 us; speedup vs baseline: 2.3719x; 2.3719x over previous
//
#include <hip/hip_runtime.h>
#include <hip/hip_bf16.h>

// GCN 2-layer: N=50000 nodes, E=800000 edges, 256 -> 64 (relu) -> 40 (log_softmax)
// Float inputs fp32 or bf16 (device-detected); edges int32 or int64 (detected).
// Pipeline: detect | CSR build (hist+scan+fill) | tiled GEMM1 | CSR gather |
//           tiled GEMM2 (bias+relu fused in staging) | CSR gather + log_softmax.

constexpr int NN   = 50000;
constexpr int NE   = 800000;
constexpr int FEAT = 256;
constexpr int HID  = 64;
constexpr int OUTD = 40;
constexpr int NC   = (NN + 255) / 256;   // 196 scan chunks

__device__ __forceinline__ float b2f(__hip_bfloat16 v) { return __bfloat162float(v); }
__device__ __forceinline__ float bflo(unsigned u) { return __uint_as_float(u << 16); }
__device__ __forceinline__ float bfhi(unsigned u) { return __uint_as_float(u & 0xffff0000u); }
__device__ __forceinline__ float loadF(const void* p, int i, bool f32) {
    return f32 ? ((const float*)p)[i] : b2f(((const __hip_bfloat16*)p)[i]);
}
__device__ __forceinline__ int loadE(const int* ei, int e, int row, bool i64) {
    long long idx = (long long)row * NE + e;
    return i64 ? ei[2 * idx] : ei[idx];
}

// ---- dtype detection: flags[0]=fp32?, flags[1]=int64 edges? ----------------
__global__ void k_detect(const unsigned* __restrict__ xw, const int* __restrict__ ew,
                         int* flags) {
    if (threadIdx.x == 0 && blockIdx.x == 0) {
        int outliers = 0;
        for (int i = 0; i < 256; i++) {
            int e = (xw[i] >> 7) & 0xFF;   // exponent of low bf16 half
            if (e < 100 || e > 140) outliers++;
        }
        flags[0] = (outliers > 64) ? 1 : 0;
        int nz = 0;
        for (int i = 1; i < 64; i += 2)
            if (ew[i] != 0) nz++;
        flags[1] = (nz == 0) ? 1 : 0;
    }
}

// ---- CSR build -------------------------------------------------------------
__global__ __launch_bounds__(256) void k_zero(int* cnt, int* cursor) {
    int i = blockIdx.x * 256 + threadIdx.x;
    if (i < NN) { cnt[i] = 0; cursor[i] = 0; }
}
__global__ __launch_bounds__(256) void k_hist(const int* __restrict__ ei,
                                              const int* __restrict__ flags, int* cnt) {
    const bool i64 = flags[1] != 0;
    int e = blockIdx.x * 256 + threadIdx.x;
    if (e < NE) atomicAdd(&cnt[loadE(ei, e, 1, i64)], 1);
}
__global__ __launch_bounds__(256) void k_rsqrt(const int* __restrict__ cnt, float* dinv) {
    int i = blockIdx.x * 256 + threadIdx.x;
    if (i < NN) dinv[i] = rsqrtf(1.0f + (float)cnt[i]);   // +1 self loop
}
__global__ __launch_bounds__(256) void k_scan1(const int* __restrict__ cnt,
                                               int* row_start, int* partial) {
    __shared__ int s[256];
    int t = threadIdx.x, i = blockIdx.x * 256 + t;
    int v = (i < NN) ? cnt[i] : 0;
    s[t] = v;
    __syncthreads();
    for (int off = 1; off < 256; off <<= 1) {
        int tmp = (t >= off) ? s[t - off] : 0;
        __syncthreads();
        s[t] += tmp;
        __syncthreads();
    }
    if (i < NN) row_start[i] = s[t] - v;       // exclusive within chunk
    if (t == 255) partial[blockIdx.x] = s[255];
}
__global__ __launch_bounds__(256) void k_scan2(int* partial) {
    __shared__ int s[256];
    int t = threadIdx.x;
    int v = (t < NC) ? partial[t] : 0;
    s[t] = v;
    __syncthreads();
    for (int off = 1; off < 256; off <<= 1) {
        int tmp = (t >= off) ? s[t - off] : 0;
        __syncthreads();
        s[t] += tmp;
        __syncthreads();
    }
    partial[t] = s[t] - v;                     // exclusive chunk offsets
}
__global__ __launch_bounds__(256) void k_scan3(int* row_start, const int* __restrict__ partial) {
    int i = blockIdx.x * 256 + threadIdx.x;
    if (i < NN) row_start[i] += partial[i >> 8];
}
__global__ __launch_bounds__(256) void k_fill(const int* __restrict__ ei,
                                              const int* __restrict__ flags,
                                              const int* __restrict__ row_start,
                                              int* cursor, int* csr_src) {
    const bool i64 = flags[1] != 0;
    int e = blockIdx.x * 256 + threadIdx.x;
    if (e < NE) {
        int s = loadE(ei, e, 0, i64), d = loadE(ei, e, 1, i64);
        int ofs = atomicAdd(&cursor[d], 1);
        csr_src[row_start[d] + ofs] = s;
    }
}

// ---- layer 1 GEMM: h1 = x @ W1 (tiled, 64 rows/block, 4x4 microtile) -------
__global__ __launch_bounds__(256) void k_gemm1(const void* __restrict__ xb,
                                               const void* __restrict__ W1,
                                               const int* __restrict__ flags,
                                               float* __restrict__ h1) {
    __shared__ __align__(16) float xt[64 * 68];
    __shared__ __align__(16) float wt[64 * 68];
    const bool f32 = flags[0] != 0;
    const int t = threadIdx.x;
    const int r0g = blockIdx.x * 64;
    const int c0 = (t & 15) * 4, r0 = (t >> 4) * 4;
    float acc[4][4] = {};
    for (int kc = 0; kc < FEAT; kc += 64) {
        __syncthreads();
#pragma unroll
        for (int j = 0; j < 4; j++) {
            int row = (t >> 4) + 16 * j;
            int gr = r0g + row;
            float4 xv = make_float4(0, 0, 0, 0);
            if (gr < NN) {
                if (f32) xv = *(const float4*)((const float*)xb + (size_t)gr * FEAT + kc + c0);
                else {
                    uint2 u = *(const uint2*)((const unsigned short*)xb + (size_t)gr * FEAT + kc + c0);
                    xv.x = bflo(u.x); xv.y = bfhi(u.x); xv.z = bflo(u.y); xv.w = bfhi(u.y);
                }
            }
            *(float4*)(xt + row * 68 + c0) = xv;
            float4 wv;
            if (f32) wv = *(const float4*)((const float*)W1 + (size_t)(kc + row) * HID + c0);
            else {
                uint2 u = *(const uint2*)((const unsigned short*)W1 + (size_t)(kc + row) * HID + c0);
                wv.x = bflo(u.x); wv.y = bfhi(u.x); wv.z = bflo(u.y); wv.w = bfhi(u.y);
            }
            *(float4*)(wt + row * 68 + c0) = wv;
        }
        __syncthreads();
#pragma unroll 2
        for (int k4 = 0; k4 < 64; k4 += 4) {
            float4 xa[4], wv[4];
#pragma unroll
            for (int ri = 0; ri < 4; ri++) xa[ri] = *(const float4*)(xt + (r0 + ri) * 68 + k4);
#pragma unroll
            for (int j = 0; j < 4; j++) wv[j] = *(const float4*)(wt + (k4 + j) * 68 + c0);
#pragma unroll
            for (int ri = 0; ri < 4; ri++) {
                acc[ri][0] += xa[ri].x * wv[0].x + xa[ri].y * wv[1].x + xa[ri].z * wv[2].x + xa[ri].w * wv[3].x;
                acc[ri][1] += xa[ri].x * wv[0].y + xa[ri].y * wv[1].y + xa[ri].z * wv[2].y + xa[ri].w * wv[3].y;
                acc[ri][2] += xa[ri].x * wv[0].z + xa[ri].y * wv[1].z + xa[ri].z * wv[2].z + xa[ri].w * wv[3].z;
                acc[ri][3] += xa[ri].x * wv[0].w + xa[ri].y * wv[1].w + xa[ri].z * wv[2].w + xa[ri].w * wv[3].w;
            }
        }
    }
#pragma unroll
    for (int ri = 0; ri < 4; ri++) {
        int gr = r0g + r0 + ri;
        if (gr < NN)
            *(float4*)(h1 + (size_t)gr * HID + c0) =
                make_float4(acc[ri][0], acc[ri][1], acc[ri][2], acc[ri][3]);
    }
}

// ---- CSR gather layer 1: agg1[n] = h1[n]*dinv_n^2 + sum_e h1[s]*dinv_s*dinv_n
__global__ __launch_bounds__(256) void k_gather1(const float* __restrict__ h1,
                                                 const float* __restrict__ dinv,
                                                 const int* __restrict__ row_start,
                                                 const int* __restrict__ cnt,
                                                 const int* __restrict__ csr_src,
                                                 float* __restrict__ agg1) {
    int n = blockIdx.x * 4 + (threadIdx.x >> 6);
    if (n >= NN) return;
    int lane = threadIdx.x & 63;
    float dn = dinv[n];
    float acc = h1[(size_t)n * HID + lane] * dn * dn;
    int rs = row_start[n], c = cnt[n];
    for (int base = 0; base < c; base += 64) {
        int m = min(64, c - base);
        int sv = 0; float wv = 0.f;
        if (lane < m) { sv = csr_src[rs + base + lane]; wv = dinv[sv] * dn; }
        for (int j = 0; j < m; j++) {
            int   s = __shfl(sv, j, 64);
            float w = __shfl(wv, j, 64);
            acc += h1[(size_t)s * HID + lane] * w;
        }
    }
    agg1[(size_t)n * HID + lane] = acc;
}

// ---- layer 2 GEMM: h2 = relu(agg1 + b1) @ W2 (bias+relu fused in staging) --
__global__ __launch_bounds__(256) void k_gemm2(const float* __restrict__ agg1,
                                               const void* __restrict__ W2,
                                               const void* __restrict__ b1,
                                               const int* __restrict__ flags,
                                               float* __restrict__ h2) {
    __shared__ __align__(16) float xt[64 * 68];
    __shared__ __align__(16) float wt[64 * 68];
    __shared__ float b1s[64];
    const bool f32 = flags[0] != 0;
    const int t = threadIdx.x;
    const int r0g = blockIdx.x * 64;
    const int c0 = (t & 15) * 4, r0 = (t >> 4) * 4;
    if (t < 64) b1s[t] = loadF(b1, t, f32);
#pragma unroll
    for (int j = 0; j < 4; j++) {            // stage W2 [64][40] -> wt[64][68] (pad cols 0)
        int k = (t >> 4) + 16 * j;
        float4 wv = make_float4(0, 0, 0, 0);
        if (c0 < OUTD) {
            if (f32) wv = *(const float4*)((const float*)W2 + (size_t)k * OUTD + c0);
            else {
                uint2 u = *(const uint2*)((const unsigned short*)W2 + (size_t)k * OUTD + c0);
                wv.x = bflo(u.x); wv.y = bfhi(u.x); wv.z = bflo(u.y); wv.w = bfhi(u.y);
            }
        }
        *(float4*)(wt + k * 68 + c0) = wv;
    }
    __syncthreads();                          // b1s ready
#pragma unroll
    for (int j = 0; j < 4; j++) {            // stage relu(agg1+b1)
        int row = (t >> 4) + 16 * j;
        int gr = r0g + row;
        float4 xv = make_float4(0, 0, 0, 0);
        if (gr < NN) {
            float4 av = *(const float4*)(agg1 + (size_t)gr * HID + c0);
            xv.x = fmaxf(av.x + b1s[c0], 0.f);
            xv.y = fmaxf(av.y + b1s[c0 + 1], 0.f);
            xv.z = fmaxf(av.z + b1s[c0 + 2], 0.f);
            xv.w = fmaxf(av.w + b1s[c0 + 3], 0.f);
        }
        *(float4*)(xt + row * 68 + c0) = xv;
    }
    __syncthreads();
    float acc[4][4] = {};
#pragma unroll 2
    for (int k4 = 0; k4 < 64; k4 += 4) {
        float4 xa[4], wv[4];
#pragma unroll
        for (int ri = 0; ri < 4; ri++) xa[ri] = *(const float4*)(xt + (r0 + ri) * 68 + k4);
#pragma unroll
        for (int j = 0; j < 4; j++) wv[j] = *(const float4*)(wt + (k4 + j) * 68 + c0);
#pragma unroll
        for (int ri = 0; ri < 4; ri++) {
            acc[ri][0] += xa[ri].x * wv[0].x + xa[ri].y * wv[1].x + xa[ri].z * wv[2].x + xa[ri].w * wv[3].x;
            acc[ri][1] += xa[ri].x * wv[0].y + xa[ri].y * wv[1].y + xa[ri].z * wv[2].y + xa[ri].w * wv[3].y;
            acc[ri][2] += xa[ri].x * wv[0].z + xa[ri].y * wv[1].z + xa[ri].z * wv[2].z + xa[ri].w * wv[3].z;
            acc[ri][3] += xa[ri].x * wv[0].w + xa[ri].y * wv[1].w + xa[ri].z * wv[2].w + xa[ri].w * wv[3].w;
        }
    }
    if (c0 < OUTD) {
#pragma unroll
        for (int ri = 0; ri < 4; ri++) {
            int gr = r0g + r0 + ri;
            if (gr < NN)
                *(float4*)(h2 + (size_t)gr * OUTD + c0) =
                    make_float4(acc[ri][0], acc[ri][1], acc[ri][2], acc[ri][3]);
        }
    }
}

// ---- CSR gather layer 2 + bias + log_softmax -------------------------------
__global__ __launch_bounds__(256) void k_gather2(const float* __restrict__ h2,
                                                 const float* __restrict__ dinv,
                                                 const int* __restrict__ row_start,
                                                 const int* __restrict__ cnt,
                                                 const int* __restrict__ csr_src,
                                                 const void* __restrict__ b2,
                                                 const int* __restrict__ flags,
                                                 void* __restrict__ out) {
    const bool f32 = flags[0] != 0;
    int n = blockIdx.x * 4 + (threadIdx.x >> 6);
    if (n >= NN) return;
    int lane = threadIdx.x & 63;
    float dn = dinv[n];
    float acc = (lane < OUTD) ? h2[(size_t)n * OUTD + lane] * dn * dn : 0.f;
    int rs = row_start[n], c = cnt[n];
    for (int base = 0; base < c; base += 64) {
        int m = min(64, c - base);
        int sv = 0; float wv = 0.f;
        if (lane < m) { sv = csr_src[rs + base + lane]; wv = dinv[sv] * dn; }
        for (int j = 0; j < m; j++) {
            int   s = __shfl(sv, j, 64);
            float w = __shfl(wv, j, 64);
            if (lane < OUTD) acc += h2[(size_t)s * OUTD + lane] * w;
        }
    }
    float v = (lane < OUTD) ? acc + loadF(b2, lane, f32) : -3.0e38f;
    float mx = v;
#pragma unroll
    for (int off = 32; off; off >>= 1) mx = fmaxf(mx, __shfl_xor(mx, off, 64));
    float ev = (lane < OUTD) ? expf(v - mx) : 0.f;
    float sm = ev;
#pragma unroll
    for (int off = 32; off; off >>= 1) sm += __shfl_xor(sm, off, 64);
    float lg = logf(sm);
    if (lane < OUTD) {
        float r = v - mx - lg;
        if (f32) ((float*)out)[(size_t)n * OUTD + lane] = r;
        else ((__hip_bfloat16*)out)[(size_t)n * OUTD + lane] = __float2bfloat16(r);
    }
}

extern "C" void kernel_launch(void* const* d_in, const int* in_sizes, int n_in,
                              void* d_out, int out_size, void* d_ws, size_t ws_size,
                              hipStream_t stream) {
    const void* x  = d_in[0];
    const int*  ei = (const int*)d_in[1];
    const void* W1 = d_in[2];
    const void* b1 = d_in[3];
    const void* W2 = d_in[4];
    const void* b2 = d_in[5];

    // ws layout (4-byte words):
    // flags[16] | dinv[50048] | cnt[50048] | cursor[50048] | row_start[50048] |
    // partial[256] | csr_src[800000] | h1[NN*64] (h2 overlays) | agg1[NN*64]
    float* ws        = (float*)d_ws;
    int*   flags     = (int*)ws;
    float* dinv      = ws + 16;
    int*   cnt       = (int*)(dinv + 50048);
    int*   cursor    = cnt + 50048;
    int*   row_start = cursor + 50048;
    int*   partial   = row_start + 50048;
    int*   csr_src   = partial + 256;
    float* h1        = (float*)(csr_src + NE);
    float* agg1      = h1 + (size_t)NN * HID;
    float* h2        = h1;   // h1 dead after gather1/gemm2 chain reads agg1

    k_detect<<<1, 64, 0, stream>>>((const unsigned*)x, ei, flags);
    k_zero  <<<(NN + 255) / 256, 256, 0, stream>>>(cnt, cursor);
    k_hist  <<<(NE + 255) / 256, 256, 0, stream>>>(ei, flags, cnt);
    k_rsqrt <<<(NN + 255) / 256, 256, 0, stream>>>(cnt, dinv);
    k_scan1 <<<NC, 256, 0, stream>>>(cnt, row_start, partial);
    k_scan2 <<<1, 256, 0, stream>>>(partial);
    k_scan3 <<<NC, 256, 0, stream>>>(row_start, partial);
    k_fill  <<<(NE + 255) / 256, 256, 0, stream>>>(ei, flags, row_start, cursor, csr_src);
    k_gemm1 <<<(NN + 63) / 64, 256, 0, stream>>>(x, W1, flags, h1);
    k_gather1<<<(NN + 3) / 4, 256, 0, stream>>>(h1, dinv, row_start, cnt, csr_src, agg1);
    k_gemm2 <<<(NN + 63) / 64, 256, 0, stream>>>(agg1, W2, b1, flags, h2);
    k_gather2<<<(NN + 3) / 4, 256, 0, stream>>>(h2, dinv, row_start, cnt, csr_src, b2, flags, d_out);
}

// Round 4
// 311.342 us; speedup vs baseline: 2.6935x; 1.1356x over previous
//
#include <hip/hip_runtime.h>
#include <hip/hip_bf16.h>

// GCN 2-layer: N=50000 nodes, E=800000 edges, 256 -> 64 (relu) -> 40 (log_softmax)
// Float inputs fp32 or bf16 (device-detected); edges int32 or int64 (detected).
// Pipeline: detect | CSR build | tiled GEMM1 (h1 stored bf16) |
//           fused gather1+bias+relu+GEMM2 (h2 stored bf16) |
//           gather2 + bias + log_softmax.
// Intermediates h1/h2 kept in bf16 to halve random-gather traffic; all
// accumulation in fp32.

constexpr int NN   = 50000;
constexpr int NE   = 800000;
constexpr int FEAT = 256;
constexpr int HID  = 64;
constexpr int OUTD = 40;
constexpr int NC   = (NN + 255) / 256;   // 196 scan chunks

__device__ __forceinline__ float b2f(__hip_bfloat16 v) { return __bfloat162float(v); }
__device__ __forceinline__ float bflo(unsigned u) { return __uint_as_float(u << 16); }
__device__ __forceinline__ float bfhi(unsigned u) { return __uint_as_float(u & 0xffff0000u); }
__device__ __forceinline__ float us2f(unsigned short u) { return __uint_as_float((unsigned)u << 16); }
__device__ __forceinline__ unsigned short f2bu(float f) {
    __hip_bfloat16 h = __float2bfloat16(f);
    return *(unsigned short*)&h;
}
__device__ __forceinline__ float loadF(const void* p, int i, bool f32) {
    return f32 ? ((const float*)p)[i] : b2f(((const __hip_bfloat16*)p)[i]);
}
__device__ __forceinline__ int loadE(const int* ei, int e, int row, bool i64) {
    long long idx = (long long)row * NE + e;
    return i64 ? ei[2 * idx] : ei[idx];
}

// ---- dtype detection: flags[0]=fp32?, flags[1]=int64 edges? ----------------
__global__ void k_detect(const unsigned* __restrict__ xw, const int* __restrict__ ew,
                         int* flags) {
    if (threadIdx.x == 0 && blockIdx.x == 0) {
        int outliers = 0;
        for (int i = 0; i < 256; i++) {
            int e = (xw[i] >> 7) & 0xFF;   // exponent of low bf16 half
            if (e < 100 || e > 140) outliers++;
        }
        flags[0] = (outliers > 64) ? 1 : 0;
        int nz = 0;
        for (int i = 1; i < 64; i += 2)
            if (ew[i] != 0) nz++;
        flags[1] = (nz == 0) ? 1 : 0;
    }
}

// ---- CSR build -------------------------------------------------------------
__global__ __launch_bounds__(256) void k_zero(int* cnt, int* cursor) {
    int i = blockIdx.x * 256 + threadIdx.x;
    if (i < NN) { cnt[i] = 0; cursor[i] = 0; }
}
__global__ __launch_bounds__(256) void k_hist(const int* __restrict__ ei,
                                              const int* __restrict__ flags, int* cnt) {
    const bool i64 = flags[1] != 0;
    int e = blockIdx.x * 256 + threadIdx.x;
    if (e < NE) atomicAdd(&cnt[loadE(ei, e, 1, i64)], 1);
}
__global__ __launch_bounds__(256) void k_rsqrt(const int* __restrict__ cnt, float* dinv) {
    int i = blockIdx.x * 256 + threadIdx.x;
    if (i < NN) dinv[i] = rsqrtf(1.0f + (float)cnt[i]);   // +1 self loop
}
__global__ __launch_bounds__(256) void k_scan1(const int* __restrict__ cnt,
                                               int* row_start, int* partial) {
    __shared__ int s[256];
    int t = threadIdx.x, i = blockIdx.x * 256 + t;
    int v = (i < NN) ? cnt[i] : 0;
    s[t] = v;
    __syncthreads();
    for (int off = 1; off < 256; off <<= 1) {
        int tmp = (t >= off) ? s[t - off] : 0;
        __syncthreads();
        s[t] += tmp;
        __syncthreads();
    }
    if (i < NN) row_start[i] = s[t] - v;       // exclusive within chunk
    if (t == 255) partial[blockIdx.x] = s[255];
}
__global__ __launch_bounds__(256) void k_scan2(int* partial) {
    __shared__ int s[256];
    int t = threadIdx.x;
    int v = (t < NC) ? partial[t] : 0;
    s[t] = v;
    __syncthreads();
    for (int off = 1; off < 256; off <<= 1) {
        int tmp = (t >= off) ? s[t - off] : 0;
        __syncthreads();
        s[t] += tmp;
        __syncthreads();
    }
    partial[t] = s[t] - v;                     // exclusive chunk offsets
}
__global__ __launch_bounds__(256) void k_scan3(int* row_start, const int* __restrict__ partial) {
    int i = blockIdx.x * 256 + threadIdx.x;
    if (i < NN) row_start[i] += partial[i >> 8];
}
__global__ __launch_bounds__(256) void k_fill(const int* __restrict__ ei,
                                              const int* __restrict__ flags,
                                              const int* __restrict__ row_start,
                                              int* cursor, int* csr_src) {
    const bool i64 = flags[1] != 0;
    int e = blockIdx.x * 256 + threadIdx.x;
    if (e < NE) {
        int s = loadE(ei, e, 0, i64), d = loadE(ei, e, 1, i64);
        int ofs = atomicAdd(&cursor[d], 1);
        csr_src[row_start[d] + ofs] = s;
    }
}

// ---- layer 1 GEMM: h1 = x @ W1 (tiled, 64 rows/block, 4x4 microtile) -------
// h1 written as bf16 (halves gather1 traffic).
__global__ __launch_bounds__(256) void k_gemm1(const void* __restrict__ xb,
                                               const void* __restrict__ W1,
                                               const int* __restrict__ flags,
                                               unsigned short* __restrict__ h1u) {
    __shared__ __align__(16) float xt[64 * 68];
    __shared__ __align__(16) float wt[64 * 68];
    const bool f32 = flags[0] != 0;
    const int t = threadIdx.x;
    const int r0g = blockIdx.x * 64;
    const int c0 = (t & 15) * 4, r0 = (t >> 4) * 4;
    float acc[4][4] = {};
    for (int kc = 0; kc < FEAT; kc += 64) {
        __syncthreads();
#pragma unroll
        for (int j = 0; j < 4; j++) {
            int row = (t >> 4) + 16 * j;
            int gr = r0g + row;
            float4 xv = make_float4(0, 0, 0, 0);
            if (gr < NN) {
                if (f32) xv = *(const float4*)((const float*)xb + (size_t)gr * FEAT + kc + c0);
                else {
                    uint2 u = *(const uint2*)((const unsigned short*)xb + (size_t)gr * FEAT + kc + c0);
                    xv.x = bflo(u.x); xv.y = bfhi(u.x); xv.z = bflo(u.y); xv.w = bfhi(u.y);
                }
            }
            *(float4*)(xt + row * 68 + c0) = xv;
            float4 wv;
            if (f32) wv = *(const float4*)((const float*)W1 + (size_t)(kc + row) * HID + c0);
            else {
                uint2 u = *(const uint2*)((const unsigned short*)W1 + (size_t)(kc + row) * HID + c0);
                wv.x = bflo(u.x); wv.y = bfhi(u.x); wv.z = bflo(u.y); wv.w = bfhi(u.y);
            }
            *(float4*)(wt + row * 68 + c0) = wv;
        }
        __syncthreads();
#pragma unroll 2
        for (int k4 = 0; k4 < 64; k4 += 4) {
            float4 xa[4], wv[4];
#pragma unroll
            for (int ri = 0; ri < 4; ri++) xa[ri] = *(const float4*)(xt + (r0 + ri) * 68 + k4);
#pragma unroll
            for (int j = 0; j < 4; j++) wv[j] = *(const float4*)(wt + (k4 + j) * 68 + c0);
#pragma unroll
            for (int ri = 0; ri < 4; ri++) {
                acc[ri][0] += xa[ri].x * wv[0].x + xa[ri].y * wv[1].x + xa[ri].z * wv[2].x + xa[ri].w * wv[3].x;
                acc[ri][1] += xa[ri].x * wv[0].y + xa[ri].y * wv[1].y + xa[ri].z * wv[2].y + xa[ri].w * wv[3].y;
                acc[ri][2] += xa[ri].x * wv[0].z + xa[ri].y * wv[1].z + xa[ri].z * wv[2].z + xa[ri].w * wv[3].z;
                acc[ri][3] += xa[ri].x * wv[0].w + xa[ri].y * wv[1].w + xa[ri].z * wv[2].w + xa[ri].w * wv[3].w;
            }
        }
    }
#pragma unroll
    for (int ri = 0; ri < 4; ri++) {
        int gr = r0g + r0 + ri;
        if (gr < NN) {
            ushort4 pk;
            pk.x = f2bu(acc[ri][0]); pk.y = f2bu(acc[ri][1]);
            pk.z = f2bu(acc[ri][2]); pk.w = f2bu(acc[ri][3]);
            *(ushort4*)(h1u + (size_t)gr * HID + c0) = pk;
        }
    }
}

// ---- fused: agg1 = gather(h1) ; g = relu(agg1+b1) ; h2 = g @ W2 (bf16 out) -
// Wave per node (grid = NN/4 exactly, no early return: __syncthreads inside).
__global__ __launch_bounds__(256) void k_gather1f(const unsigned short* __restrict__ h1u,
                                                  const float* __restrict__ dinv,
                                                  const int* __restrict__ row_start,
                                                  const int* __restrict__ cnt,
                                                  const int* __restrict__ csr_src,
                                                  const void* __restrict__ W2,
                                                  const void* __restrict__ b1,
                                                  const int* __restrict__ flags,
                                                  unsigned short* __restrict__ h2u) {
    __shared__ float w2s[HID * OUTD];        // [k][c] row-major
    __shared__ float gbuf[4][HID];
    const bool f32 = flags[0] != 0;
    const int t = threadIdx.x;
    for (int i = t; i < HID * OUTD; i += 256) w2s[i] = loadF(W2, i, f32);
    __syncthreads();
    const int wid = t >> 6, lane = t & 63;
    const int n = blockIdx.x * 4 + wid;       // always < NN (grid exact)
    const float dn = dinv[n];
    const float b1v = loadF(b1, lane, f32);
    float acc0 = us2f(h1u[(size_t)n * HID + lane]) * dn * dn;
    float acc1 = 0.f, acc2 = 0.f, acc3 = 0.f;
    const int rs = row_start[n], c = cnt[n];
    for (int base = 0; base < c; base += 64) {
        int m = min(64, c - base);
        int sv = 0; float wv = 0.f;
        if (lane < m) { sv = csr_src[rs + base + lane]; wv = dinv[sv] * dn; }
        int j = 0;
        for (; j + 4 <= m; j += 4) {
            int   s0 = __shfl(sv, j, 64),     s1 = __shfl(sv, j + 1, 64);
            int   s2 = __shfl(sv, j + 2, 64), s3 = __shfl(sv, j + 3, 64);
            float w0 = __shfl(wv, j, 64),     w1 = __shfl(wv, j + 1, 64);
            float w2 = __shfl(wv, j + 2, 64), w3 = __shfl(wv, j + 3, 64);
            acc0 += us2f(h1u[(size_t)s0 * HID + lane]) * w0;
            acc1 += us2f(h1u[(size_t)s1 * HID + lane]) * w1;
            acc2 += us2f(h1u[(size_t)s2 * HID + lane]) * w2;
            acc3 += us2f(h1u[(size_t)s3 * HID + lane]) * w3;
        }
        for (; j < m; j++) {
            int   s0 = __shfl(sv, j, 64);
            float w0 = __shfl(wv, j, 64);
            acc0 += us2f(h1u[(size_t)s0 * HID + lane]) * w0;
        }
    }
    float g = fmaxf(acc0 + acc1 + acc2 + acc3 + b1v, 0.f);
    gbuf[wid][lane] = g;
    __syncthreads();
    // matvec: h2[n][c] = sum_k g[k] * W2[k][c], lane = c
    if (lane < OUTD) {
        float o0 = 0.f, o1 = 0.f, o2 = 0.f, o3 = 0.f;
#pragma unroll 4
        for (int k = 0; k < HID; k += 4) {
            o0 += gbuf[wid][k]     * w2s[k * OUTD + lane];
            o1 += gbuf[wid][k + 1] * w2s[(k + 1) * OUTD + lane];
            o2 += gbuf[wid][k + 2] * w2s[(k + 2) * OUTD + lane];
            o3 += gbuf[wid][k + 3] * w2s[(k + 3) * OUTD + lane];
        }
        h2u[(size_t)n * OUTD + lane] = f2bu(o0 + o1 + o2 + o3);
    }
}

// ---- CSR gather layer 2 + bias + log_softmax -------------------------------
__global__ __launch_bounds__(256) void k_gather2(const unsigned short* __restrict__ h2u,
                                                 const float* __restrict__ dinv,
                                                 const int* __restrict__ row_start,
                                                 const int* __restrict__ cnt,
                                                 const int* __restrict__ csr_src,
                                                 const void* __restrict__ b2,
                                                 const int* __restrict__ flags,
                                                 void* __restrict__ out) {
    const bool f32 = flags[0] != 0;
    const int n = blockIdx.x * 4 + (threadIdx.x >> 6);   // grid exact, n < NN
    const int lane = threadIdx.x & 63;
    const float dn = dinv[n];
    const bool act = lane < OUTD;
    float acc0 = act ? us2f(h2u[(size_t)n * OUTD + lane]) * dn * dn : 0.f;
    float acc1 = 0.f, acc2 = 0.f, acc3 = 0.f;
    const int rs = row_start[n], c = cnt[n];
    for (int base = 0; base < c; base += 64) {
        int m = min(64, c - base);
        int sv = 0; float wv = 0.f;
        if (lane < m) { sv = csr_src[rs + base + lane]; wv = dinv[sv] * dn; }
        int j = 0;
        for (; j + 4 <= m; j += 4) {
            int   s0 = __shfl(sv, j, 64),     s1 = __shfl(sv, j + 1, 64);
            int   s2 = __shfl(sv, j + 2, 64), s3 = __shfl(sv, j + 3, 64);
            float w0 = __shfl(wv, j, 64),     w1 = __shfl(wv, j + 1, 64);
            float w2 = __shfl(wv, j + 2, 64), w3 = __shfl(wv, j + 3, 64);
            if (act) {
                acc0 += us2f(h2u[(size_t)s0 * OUTD + lane]) * w0;
                acc1 += us2f(h2u[(size_t)s1 * OUTD + lane]) * w1;
                acc2 += us2f(h2u[(size_t)s2 * OUTD + lane]) * w2;
                acc3 += us2f(h2u[(size_t)s3 * OUTD + lane]) * w3;
            }
        }
        for (; j < m; j++) {
            int   s0 = __shfl(sv, j, 64);
            float w0 = __shfl(wv, j, 64);
            if (act) acc0 += us2f(h2u[(size_t)s0 * OUTD + lane]) * w0;
        }
    }
    float v = act ? acc0 + acc1 + acc2 + acc3 + loadF(b2, lane, f32) : -3.0e38f;
    float mx = v;
#pragma unroll
    for (int off = 32; off; off >>= 1) mx = fmaxf(mx, __shfl_xor(mx, off, 64));
    float ev = act ? expf(v - mx) : 0.f;
    float sm = ev;
#pragma unroll
    for (int off = 32; off; off >>= 1) sm += __shfl_xor(sm, off, 64);
    float lg = logf(sm);
    if (act) {
        float r = v - mx - lg;
        if (f32) ((float*)out)[(size_t)n * OUTD + lane] = r;
        else ((__hip_bfloat16*)out)[(size_t)n * OUTD + lane] = __float2bfloat16(r);
    }
}

extern "C" void kernel_launch(void* const* d_in, const int* in_sizes, int n_in,
                              void* d_out, int out_size, void* d_ws, size_t ws_size,
                              hipStream_t stream) {
    const void* x  = d_in[0];
    const int*  ei = (const int*)d_in[1];
    const void* W1 = d_in[2];
    const void* b1 = d_in[3];
    const void* W2 = d_in[4];
    const void* b2 = d_in[5];

    // ws layout (4-byte words):
    // flags[16] | dinv[50048] | cnt[50048] | cursor[50048] | row_start[50048] |
    // partial[256] | csr_src[800000] | h1 bf16 [NN*64] | h2 bf16 [NN*40]  (~14.4 MB)
    float* ws        = (float*)d_ws;
    int*   flags     = (int*)ws;
    float* dinv      = ws + 16;
    int*   cnt       = (int*)(dinv + 50048);
    int*   cursor    = cnt + 50048;
    int*   row_start = cursor + 50048;
    int*   partial   = row_start + 50048;
    int*   csr_src   = partial + 256;
    unsigned short* h1u = (unsigned short*)(csr_src + NE);
    unsigned short* h2u = h1u + (size_t)NN * HID;   // disjoint: gather1f reads h1 while writing h2

    k_detect<<<1, 64, 0, stream>>>((const unsigned*)x, ei, flags);
    k_zero  <<<(NN + 255) / 256, 256, 0, stream>>>(cnt, cursor);
    k_hist  <<<(NE + 255) / 256, 256, 0, stream>>>(ei, flags, cnt);
    k_rsqrt <<<(NN + 255) / 256, 256, 0, stream>>>(cnt, dinv);
    k_scan1 <<<NC, 256, 0, stream>>>(cnt, row_start, partial);
    k_scan2 <<<1, 256, 0, stream>>>(partial);
    k_scan3 <<<NC, 256, 0, stream>>>(row_start, partial);
    k_fill  <<<(NE + 255) / 256, 256, 0, stream>>>(ei, flags, row_start, cursor, csr_src);
    k_gemm1 <<<(NN + 63) / 64, 256, 0, stream>>>(x, W1, flags, h1u);
    k_gather1f<<<NN / 4, 256, 0, stream>>>(h1u, dinv, row_start, cnt, csr_src, W2, b1, flags, h2u);
    k_gather2<<<NN / 4, 256, 0, stream>>>(h2u, dinv, row_start, cnt, csr_src, b2, flags, d_out);
}

// Round 5
// 289.993 us; speedup vs baseline: 2.8918x; 1.0736x over previous
//
#include <hip/hip_runtime.h>
#include <hip/hip_bf16.h>

// GCN 2-layer: N=50000 nodes, E=800000 edges, 256 -> 64 (relu) -> 40 (log_softmax)
// Float inputs fp32 or bf16 (device-detected); edges int32 or int64 (detected).
// Pipeline: zero+detect | hist | scan1(+dinv) | scan2 | scan3 | fill |
//           tiled GEMM1 (h1 bf16) | fused gather1+relu+GEMM2 (h2 bf16) |
//           gather2 + bias + log_softmax.
// Gathers: 2 nodes/wave (32-lane halves), dword loads (2 bf16 cols/lane),
// 4-way unrolled edge streams -> 8 outstanding loads/wave.

constexpr int NN   = 50000;
constexpr int NE   = 800000;
constexpr int FEAT = 256;
constexpr int HID  = 64;
constexpr int OUTD = 40;
constexpr int NC   = (NN + 255) / 256;   // 196 scan chunks

__device__ __forceinline__ float b2f(__hip_bfloat16 v) { return __bfloat162float(v); }
__device__ __forceinline__ float bflo(unsigned u) { return __uint_as_float(u << 16); }
__device__ __forceinline__ float bfhi(unsigned u) { return __uint_as_float(u & 0xffff0000u); }
__device__ __forceinline__ unsigned short f2bu(float f) {
    __hip_bfloat16 h = __float2bfloat16(f);
    return *(unsigned short*)&h;
}
__device__ __forceinline__ unsigned pack2bf(float a, float b) {
    return (unsigned)f2bu(a) | ((unsigned)f2bu(b) << 16);
}
__device__ __forceinline__ float loadF(const void* p, int i, bool f32) {
    return f32 ? ((const float*)p)[i] : b2f(((const __hip_bfloat16*)p)[i]);
}
__device__ __forceinline__ int loadE(const int* ei, int e, int row, bool i64) {
    long long idx = (long long)row * NE + e;
    return i64 ? ei[2 * idx] : ei[idx];
}

// ---- zero + dtype detection ------------------------------------------------
// flags[0]=fp32?, flags[1]=int64 edges?
__global__ __launch_bounds__(256) void k_zero(const unsigned* __restrict__ xw,
                                              const int* __restrict__ ew,
                                              int* flags, int* cnt, int* cursor) {
    int i = blockIdx.x * 256 + threadIdx.x;
    if (i < NN) { cnt[i] = 0; cursor[i] = 0; }
    if (blockIdx.x == 0 && threadIdx.x == 0) {
        int outliers = 0;
        for (int k = 0; k < 256; k++) {
            int e = (xw[k] >> 7) & 0xFF;   // exponent of low bf16 half
            if (e < 100 || e > 140) outliers++;
        }
        flags[0] = (outliers > 64) ? 1 : 0;
        int nz = 0;
        for (int k = 1; k < 64; k += 2)
            if (ew[k] != 0) nz++;
        flags[1] = (nz == 0) ? 1 : 0;
    }
}

// ---- CSR build -------------------------------------------------------------
__global__ __launch_bounds__(256) void k_hist(const int* __restrict__ ei,
                                              const int* __restrict__ flags, int* cnt) {
    const bool i64 = flags[1] != 0;
    int e = blockIdx.x * 256 + threadIdx.x;
    if (e < NE) atomicAdd(&cnt[loadE(ei, e, 1, i64)], 1);
}
__global__ __launch_bounds__(256) void k_scan1(const int* __restrict__ cnt,
                                               int* row_start, int* partial, float* dinv) {
    __shared__ int s[256];
    int t = threadIdx.x, i = blockIdx.x * 256 + t;
    int v = (i < NN) ? cnt[i] : 0;
    if (i < NN) dinv[i] = rsqrtf(1.0f + (float)v);   // +1 self loop
    s[t] = v;
    __syncthreads();
    for (int off = 1; off < 256; off <<= 1) {
        int tmp = (t >= off) ? s[t - off] : 0;
        __syncthreads();
        s[t] += tmp;
        __syncthreads();
    }
    if (i < NN) row_start[i] = s[t] - v;       // exclusive within chunk
    if (t == 255) partial[blockIdx.x] = s[255];
}
__global__ __launch_bounds__(256) void k_scan2(int* partial) {
    __shared__ int s[256];
    int t = threadIdx.x;
    int v = (t < NC) ? partial[t] : 0;
    s[t] = v;
    __syncthreads();
    for (int off = 1; off < 256; off <<= 1) {
        int tmp = (t >= off) ? s[t - off] : 0;
        __syncthreads();
        s[t] += tmp;
        __syncthreads();
    }
    partial[t] = s[t] - v;                     // exclusive chunk offsets
}
__global__ __launch_bounds__(256) void k_scan3(int* row_start, const int* __restrict__ partial) {
    int i = blockIdx.x * 256 + threadIdx.x;
    if (i < NN) row_start[i] += partial[i >> 8];
}
__global__ __launch_bounds__(256) void k_fill(const int* __restrict__ ei,
                                              const int* __restrict__ flags,
                                              const int* __restrict__ row_start,
                                              int* cursor, int* csr_src) {
    const bool i64 = flags[1] != 0;
    int e = blockIdx.x * 256 + threadIdx.x;
    if (e < NE) {
        int s = loadE(ei, e, 0, i64), d = loadE(ei, e, 1, i64);
        int ofs = atomicAdd(&cursor[d], 1);
        csr_src[row_start[d] + ofs] = s;
    }
}

// ---- layer 1 GEMM: h1 = x @ W1 (tiled, 64 rows/block, 4x4 microtile) -------
__global__ __launch_bounds__(256) void k_gemm1(const void* __restrict__ xb,
                                               const void* __restrict__ W1,
                                               const int* __restrict__ flags,
                                               unsigned short* __restrict__ h1u) {
    __shared__ __align__(16) float xt[64 * 68];
    __shared__ __align__(16) float wt[64 * 68];
    const bool f32 = flags[0] != 0;
    const int t = threadIdx.x;
    const int r0g = blockIdx.x * 64;
    const int c0 = (t & 15) * 4, r0 = (t >> 4) * 4;
    float acc[4][4] = {};
    for (int kc = 0; kc < FEAT; kc += 64) {
        __syncthreads();
#pragma unroll
        for (int j = 0; j < 4; j++) {
            int row = (t >> 4) + 16 * j;
            int gr = r0g + row;
            float4 xv = make_float4(0, 0, 0, 0);
            if (gr < NN) {
                if (f32) xv = *(const float4*)((const float*)xb + (size_t)gr * FEAT + kc + c0);
                else {
                    uint2 u = *(const uint2*)((const unsigned short*)xb + (size_t)gr * FEAT + kc + c0);
                    xv.x = bflo(u.x); xv.y = bfhi(u.x); xv.z = bflo(u.y); xv.w = bfhi(u.y);
                }
            }
            *(float4*)(xt + row * 68 + c0) = xv;
            float4 wv;
            if (f32) wv = *(const float4*)((const float*)W1 + (size_t)(kc + row) * HID + c0);
            else {
                uint2 u = *(const uint2*)((const unsigned short*)W1 + (size_t)(kc + row) * HID + c0);
                wv.x = bflo(u.x); wv.y = bfhi(u.x); wv.z = bflo(u.y); wv.w = bfhi(u.y);
            }
            *(float4*)(wt + row * 68 + c0) = wv;
        }
        __syncthreads();
#pragma unroll 2
        for (int k4 = 0; k4 < 64; k4 += 4) {
            float4 xa[4], wv[4];
#pragma unroll
            for (int ri = 0; ri < 4; ri++) xa[ri] = *(const float4*)(xt + (r0 + ri) * 68 + k4);
#pragma unroll
            for (int j = 0; j < 4; j++) wv[j] = *(const float4*)(wt + (k4 + j) * 68 + c0);
#pragma unroll
            for (int ri = 0; ri < 4; ri++) {
                acc[ri][0] += xa[ri].x * wv[0].x + xa[ri].y * wv[1].x + xa[ri].z * wv[2].x + xa[ri].w * wv[3].x;
                acc[ri][1] += xa[ri].x * wv[0].y + xa[ri].y * wv[1].y + xa[ri].z * wv[2].y + xa[ri].w * wv[3].y;
                acc[ri][2] += xa[ri].x * wv[0].z + xa[ri].y * wv[1].z + xa[ri].z * wv[2].z + xa[ri].w * wv[3].z;
                acc[ri][3] += xa[ri].x * wv[0].w + xa[ri].y * wv[1].w + xa[ri].z * wv[2].w + xa[ri].w * wv[3].w;
            }
        }
    }
#pragma unroll
    for (int ri = 0; ri < 4; ri++) {
        int gr = r0g + r0 + ri;
        if (gr < NN) {
            ushort4 pk;
            pk.x = f2bu(acc[ri][0]); pk.y = f2bu(acc[ri][1]);
            pk.z = f2bu(acc[ri][2]); pk.w = f2bu(acc[ri][3]);
            *(ushort4*)(h1u + (size_t)gr * HID + c0) = pk;
        }
    }
}

// ---- fused: agg1 = gather(h1) ; g = relu(agg1+b1) ; h2 = g @ W2 (bf16 out) -
// 2 nodes per wave: each 32-lane half owns a node; lane = 2 columns (1 dword).
// Grid = NN/8 = 6250 blocks exactly (no early return; __syncthreads inside).
__global__ __launch_bounds__(256) void k_gather1f(const unsigned* __restrict__ h1u32,
                                                  const float* __restrict__ dinv,
                                                  const int* __restrict__ row_start,
                                                  const int* __restrict__ cnt,
                                                  const int* __restrict__ csr_src,
                                                  const void* __restrict__ W2,
                                                  const void* __restrict__ b1,
                                                  const int* __restrict__ flags,
                                                  unsigned short* __restrict__ h2u) {
    __shared__ float w2s[HID * OUTD];        // [k][c] row-major
    __shared__ float gbuf[8][HID];
    const bool f32 = flags[0] != 0;
    const int t = threadIdx.x;
    for (int i = t; i < HID * OUTD; i += 256) w2s[i] = loadF(W2, i, f32);
    const int wid = t >> 6, lane = t & 63, half = lane >> 5, l32 = lane & 31;
    const int nl = wid * 2 + half;           // 0..7
    const int n = blockIdx.x * 8 + nl;       // < NN (grid exact)
    const float dn = dinv[n];
    unsigned u0 = h1u32[(size_t)n * 32 + l32];
    float aL0 = bflo(u0) * dn * dn, aH0 = bfhi(u0) * dn * dn;
    float aL1 = 0.f, aH1 = 0.f, aL2 = 0.f, aH2 = 0.f, aL3 = 0.f, aH3 = 0.f;
    const int rs = row_start[n], c = cnt[n];
    for (int base = 0; base < c; base += 32) {
        int m = min(32, c - base);
        int sv = 0; float wv = 0.f;
        if (l32 < m) { sv = csr_src[rs + base + l32]; wv = dinv[sv] * dn; }
        int j = 0;
        for (; j + 4 <= m; j += 4) {
            int   s0 = __shfl(sv, j, 32),     s1 = __shfl(sv, j + 1, 32);
            int   s2 = __shfl(sv, j + 2, 32), s3 = __shfl(sv, j + 3, 32);
            float w0 = __shfl(wv, j, 32),     w1 = __shfl(wv, j + 1, 32);
            float w2 = __shfl(wv, j + 2, 32), w3 = __shfl(wv, j + 3, 32);
            unsigned a0 = h1u32[(size_t)s0 * 32 + l32];
            unsigned a1 = h1u32[(size_t)s1 * 32 + l32];
            unsigned a2 = h1u32[(size_t)s2 * 32 + l32];
            unsigned a3 = h1u32[(size_t)s3 * 32 + l32];
            aL0 += bflo(a0) * w0; aH0 += bfhi(a0) * w0;
            aL1 += bflo(a1) * w1; aH1 += bfhi(a1) * w1;
            aL2 += bflo(a2) * w2; aH2 += bfhi(a2) * w2;
            aL3 += bflo(a3) * w3; aH3 += bfhi(a3) * w3;
        }
        for (; j < m; j++) {
            int   s0 = __shfl(sv, j, 32);
            float w0 = __shfl(wv, j, 32);
            unsigned a0 = h1u32[(size_t)s0 * 32 + l32];
            aL0 += bflo(a0) * w0; aH0 += bfhi(a0) * w0;
        }
    }
    float g0 = fmaxf(aL0 + aL1 + aL2 + aL3 + loadF(b1, 2 * l32, f32), 0.f);
    float g1 = fmaxf(aH0 + aH1 + aH2 + aH3 + loadF(b1, 2 * l32 + 1, f32), 0.f);
    gbuf[nl][2 * l32]     = g0;
    gbuf[nl][2 * l32 + 1] = g1;
    __syncthreads();
    // matvec: h2[node][col] = sum_k g[k] * W2[k][col]; 8*40=320 outputs
    for (int idx = t; idx < 8 * OUTD; idx += 256) {
        int node = idx / OUTD, col = idx % OUTD;
        float o0 = 0.f, o1 = 0.f, o2 = 0.f, o3 = 0.f;
#pragma unroll 4
        for (int k = 0; k < HID; k += 4) {
            o0 += gbuf[node][k]     * w2s[k * OUTD + col];
            o1 += gbuf[node][k + 1] * w2s[(k + 1) * OUTD + col];
            o2 += gbuf[node][k + 2] * w2s[(k + 2) * OUTD + col];
            o3 += gbuf[node][k + 3] * w2s[(k + 3) * OUTD + col];
        }
        h2u[(size_t)(blockIdx.x * 8 + node) * OUTD + col] = f2bu(o0 + o1 + o2 + o3);
    }
}

// ---- CSR gather layer 2 + bias + log_softmax -------------------------------
// 2 nodes per wave; lane covers 2 cols (dword); 20 active lanes per half.
__global__ __launch_bounds__(256) void k_gather2(const unsigned* __restrict__ h2u32,
                                                 const float* __restrict__ dinv,
                                                 const int* __restrict__ row_start,
                                                 const int* __restrict__ cnt,
                                                 const int* __restrict__ csr_src,
                                                 const void* __restrict__ b2,
                                                 const int* __restrict__ flags,
                                                 void* __restrict__ out) {
    const bool f32 = flags[0] != 0;
    const int t = threadIdx.x, lane = t & 63;
    const int half = lane >> 5, l32 = lane & 31;
    const int n = blockIdx.x * 8 + (t >> 6) * 2 + half;   // < NN (grid exact)
    const bool act = l32 < (OUTD / 2);                    // 20 dwords per row
    const float dn = dinv[n];
    unsigned u0 = act ? h2u32[(size_t)n * 20 + l32] : 0u;
    float aL0 = bflo(u0) * dn * dn, aH0 = bfhi(u0) * dn * dn;
    float aL1 = 0.f, aH1 = 0.f, aL2 = 0.f, aH2 = 0.f, aL3 = 0.f, aH3 = 0.f;
    const int rs = row_start[n], c = cnt[n];
    for (int base = 0; base < c; base += 32) {
        int m = min(32, c - base);
        int sv = 0; float wv = 0.f;
        if (l32 < m) { sv = csr_src[rs + base + l32]; wv = dinv[sv] * dn; }
        int j = 0;
        for (; j + 4 <= m; j += 4) {
            int   s0 = __shfl(sv, j, 32),     s1 = __shfl(sv, j + 1, 32);
            int   s2 = __shfl(sv, j + 2, 32), s3 = __shfl(sv, j + 3, 32);
            float w0 = __shfl(wv, j, 32),     w1 = __shfl(wv, j + 1, 32);
            float w2 = __shfl(wv, j + 2, 32), w3 = __shfl(wv, j + 3, 32);
            if (act) {
                unsigned a0 = h2u32[(size_t)s0 * 20 + l32];
                unsigned a1 = h2u32[(size_t)s1 * 20 + l32];
                unsigned a2 = h2u32[(size_t)s2 * 20 + l32];
                unsigned a3 = h2u32[(size_t)s3 * 20 + l32];
                aL0 += bflo(a0) * w0; aH0 += bfhi(a0) * w0;
                aL1 += bflo(a1) * w1; aH1 += bfhi(a1) * w1;
                aL2 += bflo(a2) * w2; aH2 += bfhi(a2) * w2;
                aL3 += bflo(a3) * w3; aH3 += bfhi(a3) * w3;
            }
        }
        for (; j < m; j++) {
            int   s0 = __shfl(sv, j, 32);
            float w0 = __shfl(wv, j, 32);
            if (act) {
                unsigned a0 = h2u32[(size_t)s0 * 20 + l32];
                aL0 += bflo(a0) * w0; aH0 += bfhi(a0) * w0;
            }
        }
    }
    float v0 = -3.0e38f, v1 = -3.0e38f;
    if (act) {
        v0 = aL0 + aL1 + aL2 + aL3 + loadF(b2, 2 * l32, f32);
        v1 = aH0 + aH1 + aH2 + aH3 + loadF(b2, 2 * l32 + 1, f32);
    }
    float mx = fmaxf(v0, v1);
#pragma unroll
    for (int off = 16; off; off >>= 1) mx = fmaxf(mx, __shfl_xor(mx, off, 32));
    float ev = act ? expf(v0 - mx) + expf(v1 - mx) : 0.f;
#pragma unroll
    for (int off = 16; off; off >>= 1) ev += __shfl_xor(ev, off, 32);
    float lg = logf(ev);
    if (act) {
        float r0 = v0 - mx - lg, r1 = v1 - mx - lg;
        if (f32) {
            float2* p = (float2*)((float*)out + (size_t)n * OUTD + 2 * l32);
            *p = make_float2(r0, r1);
        } else {
            ((unsigned*)out)[(size_t)n * 20 + l32] = pack2bf(r0, r1);
        }
    }
}

extern "C" void kernel_launch(void* const* d_in, const int* in_sizes, int n_in,
                              void* d_out, int out_size, void* d_ws, size_t ws_size,
                              hipStream_t stream) {
    const void* x  = d_in[0];
    const int*  ei = (const int*)d_in[1];
    const void* W1 = d_in[2];
    const void* b1 = d_in[3];
    const void* W2 = d_in[4];
    const void* b2 = d_in[5];

    // ws layout (4-byte words):
    // flags[16] | dinv[50048] | cnt[50048] | cursor[50048] | row_start[50048] |
    // partial[256] | csr_src[800000] | h1 bf16 [NN*64] | h2 bf16 [NN*40]  (~14.4 MB)
    float* ws        = (float*)d_ws;
    int*   flags     = (int*)ws;
    float* dinv      = ws + 16;
    int*   cnt       = (int*)(dinv + 50048);
    int*   cursor    = cnt + 50048;
    int*   row_start = cursor + 50048;
    int*   partial   = row_start + 50048;
    int*   csr_src   = partial + 256;
    unsigned short* h1u = (unsigned short*)(csr_src + NE);
    unsigned short* h2u = h1u + (size_t)NN * HID;

    k_zero  <<<(NN + 255) / 256, 256, 0, stream>>>((const unsigned*)x, ei, flags, cnt, cursor);
    k_hist  <<<(NE + 255) / 256, 256, 0, stream>>>(ei, flags, cnt);
    k_scan1 <<<NC, 256, 0, stream>>>(cnt, row_start, partial, dinv);
    k_scan2 <<<1, 256, 0, stream>>>(partial);
    k_scan3 <<<NC, 256, 0, stream>>>(row_start, partial);
    k_fill  <<<(NE + 255) / 256, 256, 0, stream>>>(ei, flags, row_start, cursor, csr_src);
    k_gemm1 <<<(NN + 63) / 64, 256, 0, stream>>>(x, W1, flags, h1u);
    k_gather1f<<<NN / 8, 256, 0, stream>>>((const unsigned*)h1u, dinv, row_start, cnt, csr_src,
                                           W2, b1, flags, h2u);
    k_gather2<<<NN / 8, 256, 0, stream>>>((const unsigned*)h2u, dinv, row_start, cnt, csr_src,
                                          b2, flags, d_out);
}

// Round 6
// 280.712 us; speedup vs baseline: 2.9874x; 1.0331x over previous
//
#include <hip/hip_runtime.h>
#include <hip/hip_bf16.h>

// GCN 2-layer: N=50000 nodes, E=800000 edges, 256 -> 64 (relu) -> 40 (log_softmax)
// Float inputs fp32 or bf16 (device-detected); edges int32 or int64 (detected).
// CSR src indices stored as ushort (NN < 65536). Fill is XCD-class partitioned:
// class = dst/6250 gives 8 contiguous CSR regions; 8 blocks per edge chunk so
// writes to a region come (heuristically) from one XCD -> no cross-XCD line
// writeback amplification. Correct regardless of block->XCD mapping.

constexpr int NN   = 50000;
constexpr int NE   = 800000;
constexpr int FEAT = 256;
constexpr int HID  = 64;
constexpr int OUTD = 40;
constexpr int NC   = (NN + 255) / 256;     // 196 scan chunks
constexpr int FCH  = 2048;                  // fill: edges per chunk
constexpr int NCH  = (NE + FCH - 1) / FCH;  // 391 chunks

__device__ __forceinline__ float b2f(__hip_bfloat16 v) { return __bfloat162float(v); }
__device__ __forceinline__ float bflo(unsigned u) { return __uint_as_float(u << 16); }
__device__ __forceinline__ float bfhi(unsigned u) { return __uint_as_float(u & 0xffff0000u); }
__device__ __forceinline__ unsigned short f2bu(float f) {
    __hip_bfloat16 h = __float2bfloat16(f);
    return *(unsigned short*)&h;
}
__device__ __forceinline__ unsigned pack2bf(float a, float b) {
    return (unsigned)f2bu(a) | ((unsigned)f2bu(b) << 16);
}
__device__ __forceinline__ float loadF(const void* p, int i, bool f32) {
    return f32 ? ((const float*)p)[i] : b2f(((const __hip_bfloat16*)p)[i]);
}
__device__ __forceinline__ int loadE(const int* ei, int e, int row, bool i64) {
    long long idx = (long long)row * NE + e;
    return i64 ? ei[2 * idx] : ei[idx];
}

// ---- zero + dtype detection ------------------------------------------------
__global__ __launch_bounds__(256) void k_zero(const unsigned* __restrict__ xw,
                                              const int* __restrict__ ew,
                                              int* flags, int* cnt, int* cursor) {
    int i = blockIdx.x * 256 + threadIdx.x;
    if (i < NN) { cnt[i] = 0; cursor[i] = 0; }
    if (blockIdx.x == 0 && threadIdx.x == 0) {
        int outliers = 0;
        for (int k = 0; k < 256; k++) {
            int e = (xw[k] >> 7) & 0xFF;   // exponent of low bf16 half
            if (e < 100 || e > 140) outliers++;
        }
        flags[0] = (outliers > 64) ? 1 : 0;
        int nz = 0;
        for (int k = 1; k < 64; k += 2)
            if (ew[k] != 0) nz++;
        flags[1] = (nz == 0) ? 1 : 0;
    }
}

// ---- CSR build -------------------------------------------------------------
__global__ __launch_bounds__(256) void k_hist(const int* __restrict__ ei,
                                              const int* __restrict__ flags, int* cnt) {
    const bool i64 = flags[1] != 0;
    int e = blockIdx.x * 256 + threadIdx.x;
    if (e < NE) atomicAdd(&cnt[loadE(ei, e, 1, i64)], 1);
}
__global__ __launch_bounds__(256) void k_scan1(const int* __restrict__ cnt,
                                               int* row_start, int* partial, float* dinv) {
    __shared__ int s[256];
    int t = threadIdx.x, i = blockIdx.x * 256 + t;
    int v = (i < NN) ? cnt[i] : 0;
    if (i < NN) dinv[i] = rsqrtf(1.0f + (float)v);   // +1 self loop
    s[t] = v;
    __syncthreads();
    for (int off = 1; off < 256; off <<= 1) {
        int tmp = (t >= off) ? s[t - off] : 0;
        __syncthreads();
        s[t] += tmp;
        __syncthreads();
    }
    if (i < NN) row_start[i] = s[t] - v;
    if (t == 255) partial[blockIdx.x] = s[255];
}
__global__ __launch_bounds__(256) void k_scan2(int* partial) {
    __shared__ int s[256];
    int t = threadIdx.x;
    int v = (t < NC) ? partial[t] : 0;
    s[t] = v;
    __syncthreads();
    for (int off = 1; off < 256; off <<= 1) {
        int tmp = (t >= off) ? s[t - off] : 0;
        __syncthreads();
        s[t] += tmp;
        __syncthreads();
    }
    partial[t] = s[t] - v;
}
__global__ __launch_bounds__(256) void k_scan3(int* row_start, const int* __restrict__ partial) {
    int i = blockIdx.x * 256 + threadIdx.x;
    if (i < NN) row_start[i] += partial[i >> 8];
}
// 8 blocks per chunk; block handles only edges whose dst-class == blockIdx&7.
// Classes are contiguous node ranges -> contiguous CSR regions -> write locality.
__global__ __launch_bounds__(256) void k_fill(const int* __restrict__ ei,
                                              const int* __restrict__ flags,
                                              const int* __restrict__ row_start,
                                              int* cursor, unsigned short* __restrict__ csr16) {
    const bool i64 = flags[1] != 0;
    const int cls = blockIdx.x & 7;
    const int e0 = (blockIdx.x >> 3) * FCH;
#pragma unroll
    for (int k = 0; k < FCH / 256; k++) {
        int e = e0 + k * 256 + threadIdx.x;
        if (e < NE) {
            int d = loadE(ei, e, 1, i64);
            if (d / 6250 == cls) {
                int s = loadE(ei, e, 0, i64);
                int ofs = atomicAdd(&cursor[d], 1);
                csr16[row_start[d] + ofs] = (unsigned short)s;
            }
        }
    }
}

// ---- layer 1 GEMM: h1 = x @ W1 (tiled, 64 rows/block, 4x4 microtile) -------
__global__ __launch_bounds__(256) void k_gemm1(const void* __restrict__ xb,
                                               const void* __restrict__ W1,
                                               const int* __restrict__ flags,
                                               unsigned short* __restrict__ h1u) {
    __shared__ __align__(16) float xt[64 * 68];
    __shared__ __align__(16) float wt[64 * 68];
    const bool f32 = flags[0] != 0;
    const int t = threadIdx.x;
    const int r0g = blockIdx.x * 64;
    const int c0 = (t & 15) * 4, r0 = (t >> 4) * 4;
    float acc[4][4] = {};
    for (int kc = 0; kc < FEAT; kc += 64) {
        __syncthreads();
#pragma unroll
        for (int j = 0; j < 4; j++) {
            int row = (t >> 4) + 16 * j;
            int gr = r0g + row;
            float4 xv = make_float4(0, 0, 0, 0);
            if (gr < NN) {
                if (f32) xv = *(const float4*)((const float*)xb + (size_t)gr * FEAT + kc + c0);
                else {
                    uint2 u = *(const uint2*)((const unsigned short*)xb + (size_t)gr * FEAT + kc + c0);
                    xv.x = bflo(u.x); xv.y = bfhi(u.x); xv.z = bflo(u.y); xv.w = bfhi(u.y);
                }
            }
            *(float4*)(xt + row * 68 + c0) = xv;
            float4 wv;
            if (f32) wv = *(const float4*)((const float*)W1 + (size_t)(kc + row) * HID + c0);
            else {
                uint2 u = *(const uint2*)((const unsigned short*)W1 + (size_t)(kc + row) * HID + c0);
                wv.x = bflo(u.x); wv.y = bfhi(u.x); wv.z = bflo(u.y); wv.w = bfhi(u.y);
            }
            *(float4*)(wt + row * 68 + c0) = wv;
        }
        __syncthreads();
#pragma unroll 2
        for (int k4 = 0; k4 < 64; k4 += 4) {
            float4 xa[4], wv[4];
#pragma unroll
            for (int ri = 0; ri < 4; ri++) xa[ri] = *(const float4*)(xt + (r0 + ri) * 68 + k4);
#pragma unroll
            for (int j = 0; j < 4; j++) wv[j] = *(const float4*)(wt + (k4 + j) * 68 + c0);
#pragma unroll
            for (int ri = 0; ri < 4; ri++) {
                acc[ri][0] += xa[ri].x * wv[0].x + xa[ri].y * wv[1].x + xa[ri].z * wv[2].x + xa[ri].w * wv[3].x;
                acc[ri][1] += xa[ri].x * wv[0].y + xa[ri].y * wv[1].y + xa[ri].z * wv[2].y + xa[ri].w * wv[3].y;
                acc[ri][2] += xa[ri].x * wv[0].z + xa[ri].y * wv[1].z + xa[ri].z * wv[2].z + xa[ri].w * wv[3].z;
                acc[ri][3] += xa[ri].x * wv[0].w + xa[ri].y * wv[1].w + xa[ri].z * wv[2].w + xa[ri].w * wv[3].w;
            }
        }
    }
#pragma unroll
    for (int ri = 0; ri < 4; ri++) {
        int gr = r0g + r0 + ri;
        if (gr < NN) {
            ushort4 pk;
            pk.x = f2bu(acc[ri][0]); pk.y = f2bu(acc[ri][1]);
            pk.z = f2bu(acc[ri][2]); pk.w = f2bu(acc[ri][3]);
            *(ushort4*)(h1u + (size_t)gr * HID + c0) = pk;
        }
    }
}

// ---- fused: agg1 = gather(h1) ; g = relu(agg1+b1) ; h2 = g @ W2 (bf16 out) -
// 2 nodes/wave (32-lane halves), dword loads, 8-deep edge unroll.
__global__ __launch_bounds__(256) void k_gather1f(const unsigned* __restrict__ h1u32,
                                                  const float* __restrict__ dinv,
                                                  const int* __restrict__ row_start,
                                                  const int* __restrict__ cnt,
                                                  const unsigned short* __restrict__ csr16,
                                                  const void* __restrict__ W2,
                                                  const void* __restrict__ b1,
                                                  const int* __restrict__ flags,
                                                  unsigned short* __restrict__ h2u) {
    __shared__ float w2s[HID * OUTD];        // [k][c] row-major
    __shared__ float gbuf[8][HID];
    const bool f32 = flags[0] != 0;
    const int t = threadIdx.x;
    for (int i = t; i < HID * OUTD; i += 256) w2s[i] = loadF(W2, i, f32);
    const int wid = t >> 6, lane = t & 63, half = lane >> 5, l32 = lane & 31;
    const int nl = wid * 2 + half;
    const int n = blockIdx.x * 8 + nl;       // < NN (grid exact)
    const float dn = dinv[n];
    unsigned u0 = h1u32[(size_t)n * 32 + l32];
    float aL0 = bflo(u0) * dn * dn, aH0 = bfhi(u0) * dn * dn;
    float aL1 = 0.f, aH1 = 0.f, aL2 = 0.f, aH2 = 0.f, aL3 = 0.f, aH3 = 0.f;
    const int rs = row_start[n], c = cnt[n];
    for (int base = 0; base < c; base += 32) {
        int m = min(32, c - base);
        int sv = 0; float wv = 0.f;
        if (l32 < m) { sv = (int)csr16[rs + base + l32]; wv = dinv[sv] * dn; }
        int j = 0;
        for (; j + 8 <= m; j += 8) {
            int   s0 = __shfl(sv, j, 32),     s1 = __shfl(sv, j + 1, 32);
            int   s2 = __shfl(sv, j + 2, 32), s3 = __shfl(sv, j + 3, 32);
            int   s4 = __shfl(sv, j + 4, 32), s5 = __shfl(sv, j + 5, 32);
            int   s6 = __shfl(sv, j + 6, 32), s7 = __shfl(sv, j + 7, 32);
            float w0 = __shfl(wv, j, 32),     w1 = __shfl(wv, j + 1, 32);
            float w2 = __shfl(wv, j + 2, 32), w3 = __shfl(wv, j + 3, 32);
            float w4 = __shfl(wv, j + 4, 32), w5 = __shfl(wv, j + 5, 32);
            float w6 = __shfl(wv, j + 6, 32), w7 = __shfl(wv, j + 7, 32);
            unsigned a0 = h1u32[(size_t)s0 * 32 + l32];
            unsigned a1 = h1u32[(size_t)s1 * 32 + l32];
            unsigned a2 = h1u32[(size_t)s2 * 32 + l32];
            unsigned a3 = h1u32[(size_t)s3 * 32 + l32];
            unsigned a4 = h1u32[(size_t)s4 * 32 + l32];
            unsigned a5 = h1u32[(size_t)s5 * 32 + l32];
            unsigned a6 = h1u32[(size_t)s6 * 32 + l32];
            unsigned a7 = h1u32[(size_t)s7 * 32 + l32];
            aL0 += bflo(a0) * w0; aH0 += bfhi(a0) * w0;
            aL1 += bflo(a1) * w1; aH1 += bfhi(a1) * w1;
            aL2 += bflo(a2) * w2; aH2 += bfhi(a2) * w2;
            aL3 += bflo(a3) * w3; aH3 += bfhi(a3) * w3;
            aL0 += bflo(a4) * w4; aH0 += bfhi(a4) * w4;
            aL1 += bflo(a5) * w5; aH1 += bfhi(a5) * w5;
            aL2 += bflo(a6) * w6; aH2 += bfhi(a6) * w6;
            aL3 += bflo(a7) * w7; aH3 += bfhi(a7) * w7;
        }
        for (; j < m; j++) {
            int   s0 = __shfl(sv, j, 32);
            float w0 = __shfl(wv, j, 32);
            unsigned a0 = h1u32[(size_t)s0 * 32 + l32];
            aL0 += bflo(a0) * w0; aH0 += bfhi(a0) * w0;
        }
    }
    float g0 = fmaxf(aL0 + aL1 + aL2 + aL3 + loadF(b1, 2 * l32, f32), 0.f);
    float g1 = fmaxf(aH0 + aH1 + aH2 + aH3 + loadF(b1, 2 * l32 + 1, f32), 0.f);
    gbuf[nl][2 * l32]     = g0;
    gbuf[nl][2 * l32 + 1] = g1;
    __syncthreads();
    for (int idx = t; idx < 8 * OUTD; idx += 256) {
        int node = idx / OUTD, col = idx % OUTD;
        float o0 = 0.f, o1 = 0.f, o2 = 0.f, o3 = 0.f;
#pragma unroll 4
        for (int k = 0; k < HID; k += 4) {
            o0 += gbuf[node][k]     * w2s[k * OUTD + col];
            o1 += gbuf[node][k + 1] * w2s[(k + 1) * OUTD + col];
            o2 += gbuf[node][k + 2] * w2s[(k + 2) * OUTD + col];
            o3 += gbuf[node][k + 3] * w2s[(k + 3) * OUTD + col];
        }
        h2u[(size_t)(blockIdx.x * 8 + node) * OUTD + col] = f2bu(o0 + o1 + o2 + o3);
    }
}

// ---- CSR gather layer 2 + bias + log_softmax -------------------------------
__global__ __launch_bounds__(256) void k_gather2(const unsigned* __restrict__ h2u32,
                                                 const float* __restrict__ dinv,
                                                 const int* __restrict__ row_start,
                                                 const int* __restrict__ cnt,
                                                 const unsigned short* __restrict__ csr16,
                                                 const void* __restrict__ b2,
                                                 const int* __restrict__ flags,
                                                 void* __restrict__ out) {
    const bool f32 = flags[0] != 0;
    const int t = threadIdx.x, lane = t & 63;
    const int half = lane >> 5, l32 = lane & 31;
    const int n = blockIdx.x * 8 + (t >> 6) * 2 + half;   // < NN (grid exact)
    const bool act = l32 < (OUTD / 2);                    // 20 dwords per row
    const float dn = dinv[n];
    unsigned u0 = act ? h2u32[(size_t)n * 20 + l32] : 0u;
    float aL0 = bflo(u0) * dn * dn, aH0 = bfhi(u0) * dn * dn;
    float aL1 = 0.f, aH1 = 0.f, aL2 = 0.f, aH2 = 0.f, aL3 = 0.f, aH3 = 0.f;
    const int rs = row_start[n], c = cnt[n];
    for (int base = 0; base < c; base += 32) {
        int m = min(32, c - base);
        int sv = 0; float wv = 0.f;
        if (l32 < m) { sv = (int)csr16[rs + base + l32]; wv = dinv[sv] * dn; }
        int j = 0;
        for (; j + 8 <= m; j += 8) {
            int   s0 = __shfl(sv, j, 32),     s1 = __shfl(sv, j + 1, 32);
            int   s2 = __shfl(sv, j + 2, 32), s3 = __shfl(sv, j + 3, 32);
            int   s4 = __shfl(sv, j + 4, 32), s5 = __shfl(sv, j + 5, 32);
            int   s6 = __shfl(sv, j + 6, 32), s7 = __shfl(sv, j + 7, 32);
            float w0 = __shfl(wv, j, 32),     w1 = __shfl(wv, j + 1, 32);
            float w2 = __shfl(wv, j + 2, 32), w3 = __shfl(wv, j + 3, 32);
            float w4 = __shfl(wv, j + 4, 32), w5 = __shfl(wv, j + 5, 32);
            float w6 = __shfl(wv, j + 6, 32), w7 = __shfl(wv, j + 7, 32);
            if (act) {
                unsigned a0 = h2u32[(size_t)s0 * 20 + l32];
                unsigned a1 = h2u32[(size_t)s1 * 20 + l32];
                unsigned a2 = h2u32[(size_t)s2 * 20 + l32];
                unsigned a3 = h2u32[(size_t)s3 * 20 + l32];
                unsigned a4 = h2u32[(size_t)s4 * 20 + l32];
                unsigned a5 = h2u32[(size_t)s5 * 20 + l32];
                unsigned a6 = h2u32[(size_t)s6 * 20 + l32];
                unsigned a7 = h2u32[(size_t)s7 * 20 + l32];
                aL0 += bflo(a0) * w0; aH0 += bfhi(a0) * w0;
                aL1 += bflo(a1) * w1; aH1 += bfhi(a1) * w1;
                aL2 += bflo(a2) * w2; aH2 += bfhi(a2) * w2;
                aL3 += bflo(a3) * w3; aH3 += bfhi(a3) * w3;
                aL0 += bflo(a4) * w4; aH0 += bfhi(a4) * w4;
                aL1 += bflo(a5) * w5; aH1 += bfhi(a5) * w5;
                aL2 += bflo(a6) * w6; aH2 += bfhi(a6) * w6;
                aL3 += bflo(a7) * w7; aH3 += bfhi(a7) * w7;
            }
        }
        for (; j < m; j++) {
            int   s0 = __shfl(sv, j, 32);
            float w0 = __shfl(wv, j, 32);
            if (act) {
                unsigned a0 = h2u32[(size_t)s0 * 20 + l32];
                aL0 += bflo(a0) * w0; aH0 += bfhi(a0) * w0;
            }
        }
    }
    float v0 = -3.0e38f, v1 = -3.0e38f;
    if (act) {
        v0 = aL0 + aL1 + aL2 + aL3 + loadF(b2, 2 * l32, f32);
        v1 = aH0 + aH1 + aH2 + aH3 + loadF(b2, 2 * l32 + 1, f32);
    }
    float mx = fmaxf(v0, v1);
#pragma unroll
    for (int off = 16; off; off >>= 1) mx = fmaxf(mx, __shfl_xor(mx, off, 32));
    float ev = act ? expf(v0 - mx) + expf(v1 - mx) : 0.f;
#pragma unroll
    for (int off = 16; off; off >>= 1) ev += __shfl_xor(ev, off, 32);
    float lg = logf(ev);
    if (act) {
        float r0 = v0 - mx - lg, r1 = v1 - mx - lg;
        if (f32) {
            float2* p = (float2*)((float*)out + (size_t)n * OUTD + 2 * l32);
            *p = make_float2(r0, r1);
        } else {
            ((unsigned*)out)[(size_t)n * 20 + l32] = pack2bf(r0, r1);
        }
    }
}

extern "C" void kernel_launch(void* const* d_in, const int* in_sizes, int n_in,
                              void* d_out, int out_size, void* d_ws, size_t ws_size,
                              hipStream_t stream) {
    const void* x  = d_in[0];
    const int*  ei = (const int*)d_in[1];
    const void* W1 = d_in[2];
    const void* b1 = d_in[3];
    const void* W2 = d_in[4];
    const void* b2 = d_in[5];

    // ws layout (4-byte words):
    // flags[16] | dinv[50048] | cnt[50048] | cursor[50048] | row_start[50048] |
    // partial[256] | csr16 ushort[800000] (=400000 words) | h1 bf16 [NN*64] |
    // h2 bf16 [NN*40]   (~12.8 MB)
    float* ws        = (float*)d_ws;
    int*   flags     = (int*)ws;
    float* dinv      = ws + 16;
    int*   cnt       = (int*)(dinv + 50048);
    int*   cursor    = cnt + 50048;
    int*   row_start = cursor + 50048;
    int*   partial   = row_start + 50048;
    unsigned short* csr16 = (unsigned short*)(partial + 256);
    unsigned short* h1u   = csr16 + NE;
    unsigned short* h2u   = h1u + (size_t)NN * HID;

    k_zero  <<<(NN + 255) / 256, 256, 0, stream>>>((const unsigned*)x, ei, flags, cnt, cursor);
    k_hist  <<<(NE + 255) / 256, 256, 0, stream>>>(ei, flags, cnt);
    k_scan1 <<<NC, 256, 0, stream>>>(cnt, row_start, partial, dinv);
    k_scan2 <<<1, 256, 0, stream>>>(partial);
    k_scan3 <<<NC, 256, 0, stream>>>(row_start, partial);
    k_fill  <<<NCH * 8, 256, 0, stream>>>(ei, flags, row_start, cursor, csr16);
    k_gemm1 <<<(NN + 63) / 64, 256, 0, stream>>>(x, W1, flags, h1u);
    k_gather1f<<<NN / 8, 256, 0, stream>>>((const unsigned*)h1u, dinv, row_start, cnt, csr16,
                                           W2, b1, flags, h2u);
    k_gather2<<<NN / 8, 256, 0, stream>>>((const unsigned*)h2u, dinv, row_start, cnt, csr16,
                                          b2, flags, d_out);
}

// Round 7
// 268.392 us; speedup vs baseline: 3.1245x; 1.0459x over previous
//
#include <hip/hip_runtime.h>
#include <hip/hip_bf16.h>

// GCN 2-layer: N=50000 nodes, E=800000 edges, 256 -> 64 (relu) -> 40 (log_softmax)
// Float inputs fp32 or bf16 (device-detected); edges int32 or int64 (detected).
// Key algebra: agg[n] = dinv[n] * ( sum_{s in N(n)} h'[s] + h'[n] ) with
// h' = h * dinv pre-scaled at production time -> gather loops need NO weight
// shuffles and NO dinv gathers (just adds of bf16-pair loads).

constexpr int NN   = 50000;
constexpr int NE   = 800000;
constexpr int FEAT = 256;
constexpr int HID  = 64;
constexpr int OUTD = 40;
constexpr int NC   = (NN + 255) / 256;     // 196 scan chunks
constexpr int FCH  = 2048;                  // fill: edges per chunk
constexpr int NCH  = (NE + FCH - 1) / FCH;  // 391 chunks

__device__ __forceinline__ float b2f(__hip_bfloat16 v) { return __bfloat162float(v); }
__device__ __forceinline__ float bflo(unsigned u) { return __uint_as_float(u << 16); }
__device__ __forceinline__ float bfhi(unsigned u) { return __uint_as_float(u & 0xffff0000u); }
__device__ __forceinline__ unsigned short f2bu(float f) {
    __hip_bfloat16 h = __float2bfloat16(f);
    return *(unsigned short*)&h;
}
__device__ __forceinline__ unsigned pack2bf(float a, float b) {
    return (unsigned)f2bu(a) | ((unsigned)f2bu(b) << 16);
}
__device__ __forceinline__ float loadF(const void* p, int i, bool f32) {
    return f32 ? ((const float*)p)[i] : b2f(((const __hip_bfloat16*)p)[i]);
}
__device__ __forceinline__ int loadE(const int* ei, int e, int row, bool i64) {
    long long idx = (long long)row * NE + e;
    return i64 ? ei[2 * idx] : ei[idx];
}

// ---- zero + dtype detection ------------------------------------------------
__global__ __launch_bounds__(256) void k_zero(const unsigned* __restrict__ xw,
                                              const int* __restrict__ ew,
                                              int* flags, int* cnt, int* cursor) {
    int i = blockIdx.x * 256 + threadIdx.x;
    if (i < NN) { cnt[i] = 0; cursor[i] = 0; }
    if (blockIdx.x == 0 && threadIdx.x == 0) {
        int outliers = 0;
        for (int k = 0; k < 256; k++) {
            int e = (xw[k] >> 7) & 0xFF;   // exponent of low bf16 half
            if (e < 100 || e > 140) outliers++;
        }
        flags[0] = (outliers > 64) ? 1 : 0;
        int nz = 0;
        for (int k = 1; k < 64; k += 2)
            if (ew[k] != 0) nz++;
        flags[1] = (nz == 0) ? 1 : 0;
    }
}

// ---- CSR build -------------------------------------------------------------
__global__ __launch_bounds__(256) void k_hist(const int* __restrict__ ei,
                                              const int* __restrict__ flags, int* cnt) {
    const bool i64 = flags[1] != 0;
    int e = blockIdx.x * 256 + threadIdx.x;
    if (e < NE) atomicAdd(&cnt[loadE(ei, e, 1, i64)], 1);
}
__global__ __launch_bounds__(256) void k_scan1(const int* __restrict__ cnt,
                                               int* row_start, int* partial, float* dinv) {
    __shared__ int s[256];
    int t = threadIdx.x, i = blockIdx.x * 256 + t;
    int v = (i < NN) ? cnt[i] : 0;
    if (i < NN) dinv[i] = rsqrtf(1.0f + (float)v);   // +1 self loop
    s[t] = v;
    __syncthreads();
    for (int off = 1; off < 256; off <<= 1) {
        int tmp = (t >= off) ? s[t - off] : 0;
        __syncthreads();
        s[t] += tmp;
        __syncthreads();
    }
    if (i < NN) row_start[i] = s[t] - v;
    if (t == 255) partial[blockIdx.x] = s[255];
}
// scan3 with inlined chunk-offset reduction (replaces separate scan2 kernel):
// block b needs sum of partial[0..b-1]; 256 threads reduce the masked array.
__global__ __launch_bounds__(256) void k_scan3(int* row_start, const int* __restrict__ partial) {
    __shared__ int red[4];
    const int t = threadIdx.x;
    int v = (t < NC && t < (int)blockIdx.x) ? partial[t] : 0;
#pragma unroll
    for (int off = 32; off; off >>= 1) v += __shfl_xor(v, off, 64);
    if ((t & 63) == 0) red[t >> 6] = v;
    __syncthreads();
    int total = red[0] + red[1] + red[2] + red[3];
    int i = blockIdx.x * 256 + t;
    if (i < NN) row_start[i] += total;
}
// 8 blocks per chunk; block handles only edges whose dst-class == blockIdx&7.
__global__ __launch_bounds__(256) void k_fill(const int* __restrict__ ei,
                                              const int* __restrict__ flags,
                                              const int* __restrict__ row_start,
                                              int* cursor, unsigned short* __restrict__ csr16) {
    const bool i64 = flags[1] != 0;
    const int cls = blockIdx.x & 7;
    const int e0 = (blockIdx.x >> 3) * FCH;
#pragma unroll
    for (int k = 0; k < FCH / 256; k++) {
        int e = e0 + k * 256 + threadIdx.x;
        if (e < NE) {
            int d = loadE(ei, e, 1, i64);
            if (d / 6250 == cls) {
                int s = loadE(ei, e, 0, i64);
                int ofs = atomicAdd(&cursor[d], 1);
                csr16[row_start[d] + ofs] = (unsigned short)s;
            }
        }
    }
}

// ---- layer 1 GEMM: h1' = (x @ W1) * dinv[row]  (bf16 out) ------------------
__global__ __launch_bounds__(256) void k_gemm1(const void* __restrict__ xb,
                                               const void* __restrict__ W1,
                                               const float* __restrict__ dinv,
                                               const int* __restrict__ flags,
                                               unsigned short* __restrict__ h1u) {
    __shared__ __align__(16) float xt[64 * 68];
    __shared__ __align__(16) float wt[64 * 68];
    const bool f32 = flags[0] != 0;
    const int t = threadIdx.x;
    const int r0g = blockIdx.x * 64;
    const int c0 = (t & 15) * 4, r0 = (t >> 4) * 4;
    float acc[4][4] = {};
    for (int kc = 0; kc < FEAT; kc += 64) {
        __syncthreads();
#pragma unroll
        for (int j = 0; j < 4; j++) {
            int row = (t >> 4) + 16 * j;
            int gr = r0g + row;
            float4 xv = make_float4(0, 0, 0, 0);
            if (gr < NN) {
                if (f32) xv = *(const float4*)((const float*)xb + (size_t)gr * FEAT + kc + c0);
                else {
                    uint2 u = *(const uint2*)((const unsigned short*)xb + (size_t)gr * FEAT + kc + c0);
                    xv.x = bflo(u.x); xv.y = bfhi(u.x); xv.z = bflo(u.y); xv.w = bfhi(u.y);
                }
            }
            *(float4*)(xt + row * 68 + c0) = xv;
            float4 wv;
            if (f32) wv = *(const float4*)((const float*)W1 + (size_t)(kc + row) * HID + c0);
            else {
                uint2 u = *(const uint2*)((const unsigned short*)W1 + (size_t)(kc + row) * HID + c0);
                wv.x = bflo(u.x); wv.y = bfhi(u.x); wv.z = bflo(u.y); wv.w = bfhi(u.y);
            }
            *(float4*)(wt + row * 68 + c0) = wv;
        }
        __syncthreads();
#pragma unroll 2
        for (int k4 = 0; k4 < 64; k4 += 4) {
            float4 xa[4], wv[4];
#pragma unroll
            for (int ri = 0; ri < 4; ri++) xa[ri] = *(const float4*)(xt + (r0 + ri) * 68 + k4);
#pragma unroll
            for (int j = 0; j < 4; j++) wv[j] = *(const float4*)(wt + (k4 + j) * 68 + c0);
#pragma unroll
            for (int ri = 0; ri < 4; ri++) {
                acc[ri][0] += xa[ri].x * wv[0].x + xa[ri].y * wv[1].x + xa[ri].z * wv[2].x + xa[ri].w * wv[3].x;
                acc[ri][1] += xa[ri].x * wv[0].y + xa[ri].y * wv[1].y + xa[ri].z * wv[2].y + xa[ri].w * wv[3].y;
                acc[ri][2] += xa[ri].x * wv[0].z + xa[ri].y * wv[1].z + xa[ri].z * wv[2].z + xa[ri].w * wv[3].z;
                acc[ri][3] += xa[ri].x * wv[0].w + xa[ri].y * wv[1].w + xa[ri].z * wv[2].w + xa[ri].w * wv[3].w;
            }
        }
    }
#pragma unroll
    for (int ri = 0; ri < 4; ri++) {
        int gr = r0g + r0 + ri;
        if (gr < NN) {
            float di = dinv[gr];
            ushort4 pk;
            pk.x = f2bu(acc[ri][0] * di); pk.y = f2bu(acc[ri][1] * di);
            pk.z = f2bu(acc[ri][2] * di); pk.w = f2bu(acc[ri][3] * di);
            *(ushort4*)(h1u + (size_t)gr * HID + c0) = pk;
        }
    }
}

// ---- fused: s = sum h1'[{n}uN(n)] ; g = relu(dn*s + b1) ; h2' = dn*(g@W2) --
// 2 nodes/wave (32-lane halves), dword loads, 8-deep unroll, no weight math.
__global__ __launch_bounds__(256) void k_gather1f(const unsigned* __restrict__ h1u32,
                                                  const float* __restrict__ dinv,
                                                  const int* __restrict__ row_start,
                                                  const int* __restrict__ cnt,
                                                  const unsigned short* __restrict__ csr16,
                                                  const void* __restrict__ W2,
                                                  const void* __restrict__ b1,
                                                  const int* __restrict__ flags,
                                                  unsigned short* __restrict__ h2u) {
    __shared__ __align__(16) float w2t[OUTD * 68];   // [col][k], stride 68
    __shared__ __align__(16) float gbuf[8 * 68];     // [node][k], stride 68
    __shared__ float dns[8];
    const bool f32 = flags[0] != 0;
    const int t = threadIdx.x;
    for (int i = t; i < HID * OUTD; i += 256) {
        int c = i % OUTD, k = i / OUTD;
        w2t[c * 68 + k] = loadF(W2, (size_t)k * OUTD + c, f32);
    }
    const int wid = t >> 6, lane = t & 63, half = lane >> 5, l32 = lane & 31;
    const int nl = wid * 2 + half;
    const int n = blockIdx.x * 8 + nl;       // < NN (grid exact)
    const float dn = dinv[n];
    unsigned u0 = h1u32[(size_t)n * 32 + l32];
    float aL0 = bflo(u0), aH0 = bfhi(u0);    // self term (weight folded)
    float aL1 = 0.f, aH1 = 0.f, aL2 = 0.f, aH2 = 0.f, aL3 = 0.f, aH3 = 0.f;
    const int rs = row_start[n], c = cnt[n];
    for (int base = 0; base < c; base += 32) {
        int m = min(32, c - base);
        int sv = (l32 < m) ? (int)csr16[rs + base + l32] : 0;
        int j = 0;
        for (; j + 8 <= m; j += 8) {
            int s0 = __shfl(sv, j, 32),     s1 = __shfl(sv, j + 1, 32);
            int s2 = __shfl(sv, j + 2, 32), s3 = __shfl(sv, j + 3, 32);
            int s4 = __shfl(sv, j + 4, 32), s5 = __shfl(sv, j + 5, 32);
            int s6 = __shfl(sv, j + 6, 32), s7 = __shfl(sv, j + 7, 32);
            unsigned a0 = h1u32[(size_t)s0 * 32 + l32];
            unsigned a1 = h1u32[(size_t)s1 * 32 + l32];
            unsigned a2 = h1u32[(size_t)s2 * 32 + l32];
            unsigned a3 = h1u32[(size_t)s3 * 32 + l32];
            unsigned a4 = h1u32[(size_t)s4 * 32 + l32];
            unsigned a5 = h1u32[(size_t)s5 * 32 + l32];
            unsigned a6 = h1u32[(size_t)s6 * 32 + l32];
            unsigned a7 = h1u32[(size_t)s7 * 32 + l32];
            aL0 += bflo(a0); aH0 += bfhi(a0);
            aL1 += bflo(a1); aH1 += bfhi(a1);
            aL2 += bflo(a2); aH2 += bfhi(a2);
            aL3 += bflo(a3); aH3 += bfhi(a3);
            aL0 += bflo(a4); aH0 += bfhi(a4);
            aL1 += bflo(a5); aH1 += bfhi(a5);
            aL2 += bflo(a6); aH2 += bfhi(a6);
            aL3 += bflo(a7); aH3 += bfhi(a7);
        }
        for (; j < m; j++) {
            int s0 = __shfl(sv, j, 32);
            unsigned a0 = h1u32[(size_t)s0 * 32 + l32];
            aL0 += bflo(a0); aH0 += bfhi(a0);
        }
    }
    float g0 = fmaxf(dn * (aL0 + aL1 + aL2 + aL3) + loadF(b1, 2 * l32, f32), 0.f);
    float g1 = fmaxf(dn * (aH0 + aH1 + aH2 + aH3) + loadF(b1, 2 * l32 + 1, f32), 0.f);
    *(float2*)(gbuf + nl * 68 + 2 * l32) = make_float2(g0, g1);
    if (l32 == 0) dns[nl] = dn;
    __syncthreads();
    // matvec: h2'[node][col] = dns[node] * sum_k g[k]*W2[k][col]
    for (int idx = t; idx < 8 * OUTD; idx += 256) {
        int node = idx / OUTD, col = idx % OUTD;
        const float4* gp = (const float4*)(gbuf + node * 68);
        const float4* wp = (const float4*)(w2t + col * 68);
        float o = 0.f;
#pragma unroll 4
        for (int k4 = 0; k4 < 16; k4++) {
            float4 a = gp[k4], b = wp[k4];
            o += a.x * b.x + a.y * b.y + a.z * b.z + a.w * b.w;
        }
        h2u[(size_t)(blockIdx.x * 8 + node) * OUTD + col] = f2bu(o * dns[node]);
    }
}

// ---- CSR gather layer 2 + bias + log_softmax -------------------------------
__global__ __launch_bounds__(256) void k_gather2(const unsigned* __restrict__ h2u32,
                                                 const float* __restrict__ dinv,
                                                 const int* __restrict__ row_start,
                                                 const int* __restrict__ cnt,
                                                 const unsigned short* __restrict__ csr16,
                                                 const void* __restrict__ b2,
                                                 const int* __restrict__ flags,
                                                 void* __restrict__ out) {
    const bool f32 = flags[0] != 0;
    const int t = threadIdx.x, lane = t & 63;
    const int half = lane >> 5, l32 = lane & 31;
    const int n = blockIdx.x * 8 + (t >> 6) * 2 + half;   // < NN (grid exact)
    const bool act = l32 < (OUTD / 2);                    // 20 dwords per row
    const float dn = dinv[n];
    unsigned u0 = act ? h2u32[(size_t)n * 20 + l32] : 0u;
    float aL0 = bflo(u0), aH0 = bfhi(u0);
    float aL1 = 0.f, aH1 = 0.f, aL2 = 0.f, aH2 = 0.f, aL3 = 0.f, aH3 = 0.f;
    const int rs = row_start[n], c = cnt[n];
    for (int base = 0; base < c; base += 32) {
        int m = min(32, c - base);
        int sv = (l32 < m) ? (int)csr16[rs + base + l32] : 0;
        int j = 0;
        for (; j + 8 <= m; j += 8) {
            int s0 = __shfl(sv, j, 32),     s1 = __shfl(sv, j + 1, 32);
            int s2 = __shfl(sv, j + 2, 32), s3 = __shfl(sv, j + 3, 32);
            int s4 = __shfl(sv, j + 4, 32), s5 = __shfl(sv, j + 5, 32);
            int s6 = __shfl(sv, j + 6, 32), s7 = __shfl(sv, j + 7, 32);
            if (act) {
                unsigned a0 = h2u32[(size_t)s0 * 20 + l32];
                unsigned a1 = h2u32[(size_t)s1 * 20 + l32];
                unsigned a2 = h2u32[(size_t)s2 * 20 + l32];
                unsigned a3 = h2u32[(size_t)s3 * 20 + l32];
                unsigned a4 = h2u32[(size_t)s4 * 20 + l32];
                unsigned a5 = h2u32[(size_t)s5 * 20 + l32];
                unsigned a6 = h2u32[(size_t)s6 * 20 + l32];
                unsigned a7 = h2u32[(size_t)s7 * 20 + l32];
                aL0 += bflo(a0); aH0 += bfhi(a0);
                aL1 += bflo(a1); aH1 += bfhi(a1);
                aL2 += bflo(a2); aH2 += bfhi(a2);
                aL3 += bflo(a3); aH3 += bfhi(a3);
                aL0 += bflo(a4); aH0 += bfhi(a4);
                aL1 += bflo(a5); aH1 += bfhi(a5);
                aL2 += bflo(a6); aH2 += bfhi(a6);
                aL3 += bflo(a7); aH3 += bfhi(a7);
            }
        }
        for (; j < m; j++) {
            int s0 = __shfl(sv, j, 32);
            if (act) {
                unsigned a0 = h2u32[(size_t)s0 * 20 + l32];
                aL0 += bflo(a0); aH0 += bfhi(a0);
            }
        }
    }
    float v0 = -3.0e38f, v1 = -3.0e38f;
    if (act) {
        v0 = dn * (aL0 + aL1 + aL2 + aL3) + loadF(b2, 2 * l32, f32);
        v1 = dn * (aH0 + aH1 + aH2 + aH3) + loadF(b2, 2 * l32 + 1, f32);
    }
    float mx = fmaxf(v0, v1);
#pragma unroll
    for (int off = 16; off; off >>= 1) mx = fmaxf(mx, __shfl_xor(mx, off, 32));
    float ev = act ? expf(v0 - mx) + expf(v1 - mx) : 0.f;
#pragma unroll
    for (int off = 16; off; off >>= 1) ev += __shfl_xor(ev, off, 32);
    float lg = logf(ev);
    if (act) {
        float r0 = v0 - mx - lg, r1 = v1 - mx - lg;
        if (f32) {
            float2* p = (float2*)((float*)out + (size_t)n * OUTD + 2 * l32);
            *p = make_float2(r0, r1);
        } else {
            ((unsigned*)out)[(size_t)n * 20 + l32] = pack2bf(r0, r1);
        }
    }
}

extern "C" void kernel_launch(void* const* d_in, const int* in_sizes, int n_in,
                              void* d_out, int out_size, void* d_ws, size_t ws_size,
                              hipStream_t stream) {
    const void* x  = d_in[0];
    const int*  ei = (const int*)d_in[1];
    const void* W1 = d_in[2];
    const void* b1 = d_in[3];
    const void* W2 = d_in[4];
    const void* b2 = d_in[5];

    // ws layout (4-byte words):
    // flags[16] | dinv[50048] | cnt[50048] | cursor[50048] | row_start[50048] |
    // partial[256] | csr16 ushort[800000] | h1' bf16 [NN*64] | h2' bf16 [NN*40]
    float* ws        = (float*)d_ws;
    int*   flags     = (int*)ws;
    float* dinv      = ws + 16;
    int*   cnt       = (int*)(dinv + 50048);
    int*   cursor    = cnt + 50048;
    int*   row_start = cursor + 50048;
    int*   partial   = row_start + 50048;
    unsigned short* csr16 = (unsigned short*)(partial + 256);
    unsigned short* h1u   = csr16 + NE;
    unsigned short* h2u   = h1u + (size_t)NN * HID;

    k_zero  <<<(NN + 255) / 256, 256, 0, stream>>>((const unsigned*)x, ei, flags, cnt, cursor);
    k_hist  <<<(NE + 255) / 256, 256, 0, stream>>>(ei, flags, cnt);
    k_scan1 <<<NC, 256, 0, stream>>>(cnt, row_start, partial, dinv);
    k_scan3 <<<NC, 256, 0, stream>>>(row_start, partial);
    k_fill  <<<NCH * 8, 256, 0, stream>>>(ei, flags, row_start, cursor, csr16);
    k_gemm1 <<<(NN + 63) / 64, 256, 0, stream>>>(x, W1, dinv, flags, h1u);
    k_gather1f<<<NN / 8, 256, 0, stream>>>((const unsigned*)h1u, dinv, row_start, cnt, csr16,
                                           W2, b1, flags, h2u);
    k_gather2<<<NN / 8, 256, 0, stream>>>((const unsigned*)h2u, dinv, row_start, cnt, csr16,
                                          b2, flags, d_out);
}

// Round 8
// 257.019 us; speedup vs baseline: 3.2628x; 1.0442x over previous
//
#include <hip/hip_runtime.h>
#include <hip/hip_bf16.h>

// GCN 2-layer: N=50000 nodes, E=800000 edges, 256 -> 64 (relu) -> 40 (log_softmax)
// Float inputs fp32 or bf16 (device-detected); edges int32 or int64 (detected).
// agg[n] = dinv[n] * ( sum_{s in N(n)} h'[s] + h'[n] ), h' = h*dinv pre-scaled.
// gemm1 uses MFMA 16x16x32 bf16: W1^T in LDS, A-frags straight from global x.

constexpr int NN   = 50000;
constexpr int NE   = 800000;
constexpr int FEAT = 256;
constexpr int HID  = 64;
constexpr int OUTD = 40;
constexpr int NC   = (NN + 255) / 256;     // 196 scan chunks
constexpr int FCH  = 2048;                  // fill: edges per chunk
constexpr int NCH  = (NE + FCH - 1) / FCH;  // 391 chunks

typedef short bf16x8 __attribute__((ext_vector_type(8)));
typedef float f32x4  __attribute__((ext_vector_type(4)));

__device__ __forceinline__ float b2f(__hip_bfloat16 v) { return __bfloat162float(v); }
__device__ __forceinline__ float bflo(unsigned u) { return __uint_as_float(u << 16); }
__device__ __forceinline__ float bfhi(unsigned u) { return __uint_as_float(u & 0xffff0000u); }
__device__ __forceinline__ unsigned short f2bu(float f) {
    __hip_bfloat16 h = __float2bfloat16(f);
    return *(unsigned short*)&h;
}
__device__ __forceinline__ unsigned pack2bf(float a, float b) {
    return (unsigned)f2bu(a) | ((unsigned)f2bu(b) << 16);
}
__device__ __forceinline__ float loadF(const void* p, int i, bool f32) {
    return f32 ? ((const float*)p)[i] : b2f(((const __hip_bfloat16*)p)[i]);
}
__device__ __forceinline__ int loadE(const int* ei, int e, int row, bool i64) {
    long long idx = (long long)row * NE + e;
    return i64 ? ei[2 * idx] : ei[idx];
}
__device__ __forceinline__ bf16x8 pack8(float4 a, float4 b) {
    bf16x8 r;
    r[0] = (short)f2bu(a.x); r[1] = (short)f2bu(a.y);
    r[2] = (short)f2bu(a.z); r[3] = (short)f2bu(a.w);
    r[4] = (short)f2bu(b.x); r[5] = (short)f2bu(b.y);
    r[6] = (short)f2bu(b.z); r[7] = (short)f2bu(b.w);
    return r;
}

// ---- zero + dtype detection ------------------------------------------------
__global__ __launch_bounds__(256) void k_zero(const unsigned* __restrict__ xw,
                                              const int* __restrict__ ew,
                                              int* flags, int* cnt, int* cursor) {
    int i = blockIdx.x * 256 + threadIdx.x;
    if (i < NN) { cnt[i] = 0; cursor[i] = 0; }
    if (blockIdx.x == 0 && threadIdx.x == 0) {
        int outliers = 0;
        for (int k = 0; k < 256; k++) {
            int e = (xw[k] >> 7) & 0xFF;   // exponent of low bf16 half
            if (e < 100 || e > 140) outliers++;
        }
        flags[0] = (outliers > 64) ? 1 : 0;
        int nz = 0;
        for (int k = 1; k < 64; k += 2)
            if (ew[k] != 0) nz++;
        flags[1] = (nz == 0) ? 1 : 0;
    }
}

// ---- CSR build -------------------------------------------------------------
__global__ __launch_bounds__(256) void k_hist(const int* __restrict__ ei,
                                              const int* __restrict__ flags, int* cnt) {
    const bool i64 = flags[1] != 0;
    int e = blockIdx.x * 256 + threadIdx.x;
    if (e < NE) atomicAdd(&cnt[loadE(ei, e, 1, i64)], 1);
}
__global__ __launch_bounds__(256) void k_scan1(const int* __restrict__ cnt,
                                               int* row_start, int* partial, float* dinv) {
    __shared__ int s[256];
    int t = threadIdx.x, i = blockIdx.x * 256 + t;
    int v = (i < NN) ? cnt[i] : 0;
    if (i < NN) dinv[i] = rsqrtf(1.0f + (float)v);   // +1 self loop
    s[t] = v;
    __syncthreads();
    for (int off = 1; off < 256; off <<= 1) {
        int tmp = (t >= off) ? s[t - off] : 0;
        __syncthreads();
        s[t] += tmp;
        __syncthreads();
    }
    if (i < NN) row_start[i] = s[t] - v;
    if (t == 255) partial[blockIdx.x] = s[255];
}
__global__ __launch_bounds__(256) void k_scan3(int* row_start, const int* __restrict__ partial) {
    __shared__ int red[4];
    const int t = threadIdx.x;
    int v = (t < NC && t < (int)blockIdx.x) ? partial[t] : 0;
#pragma unroll
    for (int off = 32; off; off >>= 1) v += __shfl_xor(v, off, 64);
    if ((t & 63) == 0) red[t >> 6] = v;
    __syncthreads();
    int total = red[0] + red[1] + red[2] + red[3];
    int i = blockIdx.x * 256 + t;
    if (i < NN) row_start[i] += total;
}
__global__ __launch_bounds__(256) void k_fill(const int* __restrict__ ei,
                                              const int* __restrict__ flags,
                                              const int* __restrict__ row_start,
                                              int* cursor, unsigned short* __restrict__ csr16) {
    const bool i64 = flags[1] != 0;
    const int cls = blockIdx.x & 7;
    const int e0 = (blockIdx.x >> 3) * FCH;
#pragma unroll
    for (int k = 0; k < FCH / 256; k++) {
        int e = e0 + k * 256 + threadIdx.x;
        if (e < NE) {
            int d = loadE(ei, e, 1, i64);
            if (d / 6250 == cls) {
                int s = loadE(ei, e, 0, i64);
                int ofs = atomicAdd(&cursor[d], 1);
                csr16[row_start[d] + ofs] = (unsigned short)s;
            }
        }
    }
}

// ---- layer 1 GEMM (MFMA): h1' = (x @ W1) * dinv[row]  (bf16 out) -----------
// Block: 64 rows x 64 cols, 4 waves; wave w owns rows w*16..w*16+15.
// W1^T in LDS bf16 [n][k] stride 264; A-frags from global x (prefetched).
__global__ __launch_bounds__(256) void k_gemm1(const void* __restrict__ xb,
                                               const void* __restrict__ W1,
                                               const float* __restrict__ dinv,
                                               const int* __restrict__ flags,
                                               unsigned short* __restrict__ h1u) {
    __shared__ __align__(16) unsigned short wt16[64 * 264];
    const bool f32 = flags[0] != 0;
    const int t = threadIdx.x;
    // stage W1^T (W1 is [FEAT=256][HID=64] row-major; linear i = k*64 + n)
    if (f32) {
        const float* wf = (const float*)W1;
        for (int i = t * 4; i < FEAT * HID; i += 1024) {
            float4 w = *(const float4*)(wf + i);
            int k = i >> 6, n0 = i & 63;
            wt16[(n0 + 0) * 264 + k] = f2bu(w.x);
            wt16[(n0 + 1) * 264 + k] = f2bu(w.y);
            wt16[(n0 + 2) * 264 + k] = f2bu(w.z);
            wt16[(n0 + 3) * 264 + k] = f2bu(w.w);
        }
    } else {
        const unsigned short* wu = (const unsigned short*)W1;
        for (int i = t * 4; i < FEAT * HID; i += 1024) {
            ushort4 w = *(const ushort4*)(wu + i);
            int k = i >> 6, n0 = i & 63;
            wt16[(n0 + 0) * 264 + k] = w.x;
            wt16[(n0 + 1) * 264 + k] = w.y;
            wt16[(n0 + 2) * 264 + k] = w.z;
            wt16[(n0 + 3) * 264 + k] = w.w;
        }
    }
    const int wv = t >> 6, lane = t & 63, l15 = lane & 15, quad = lane >> 4;
    const int gr = blockIdx.x * 64 + wv * 16 + l15;   // A row for this lane
    const bool rowok = gr < NN;
    f32x4 acc[4];
#pragma unroll
    for (int nt = 0; nt < 4; nt++) acc[nt] = (f32x4){0.f, 0.f, 0.f, 0.f};
    __syncthreads();

    if (f32) {
        const float* xr = (const float*)xb + (size_t)gr * FEAT + quad * 8;
        float4 z4 = make_float4(0, 0, 0, 0);
        float4 c0 = rowok ? *(const float4*)xr : z4;
        float4 c1 = rowok ? *(const float4*)(xr + 4) : z4;
#pragma unroll
        for (int ks = 0; ks < 8; ks++) {
            float4 n0 = z4, n1 = z4;
            if (ks < 7 && rowok) {
                n0 = *(const float4*)(xr + (ks + 1) * 32);
                n1 = *(const float4*)(xr + (ks + 1) * 32 + 4);
            }
            bf16x8 a = pack8(c0, c1);
            const unsigned short* wk = wt16 + ks * 32 + quad * 8;
#pragma unroll
            for (int nt = 0; nt < 4; nt++) {
                bf16x8 b = *(const bf16x8*)(wk + (size_t)(nt * 16 + l15) * 264);
                acc[nt] = __builtin_amdgcn_mfma_f32_16x16x32_bf16(a, b, acc[nt], 0, 0, 0);
            }
            c0 = n0; c1 = n1;
        }
    } else {
        const unsigned short* xr = (const unsigned short*)xb + (size_t)gr * FEAT + quad * 8;
        bf16x8 zz = (bf16x8){0, 0, 0, 0, 0, 0, 0, 0};
        bf16x8 cur = rowok ? *(const bf16x8*)xr : zz;
#pragma unroll
        for (int ks = 0; ks < 8; ks++) {
            bf16x8 nxt = zz;
            if (ks < 7 && rowok) nxt = *(const bf16x8*)(xr + (ks + 1) * 32);
            const unsigned short* wk = wt16 + ks * 32 + quad * 8;
#pragma unroll
            for (int nt = 0; nt < 4; nt++) {
                bf16x8 b = *(const bf16x8*)(wk + (size_t)(nt * 16 + l15) * 264);
                acc[nt] = __builtin_amdgcn_mfma_f32_16x16x32_bf16(cur, b, acc[nt], 0, 0, 0);
            }
            cur = nxt;
        }
    }
    // epilogue: D[row=quad*4+r][col=l15] per n-tile; scale by dinv, store bf16
    const int rbase = blockIdx.x * 64 + wv * 16 + quad * 4;
    float dv[4];
#pragma unroll
    for (int r = 0; r < 4; r++) dv[r] = (rbase + r < NN) ? dinv[rbase + r] : 0.f;
#pragma unroll
    for (int r = 0; r < 4; r++) {
        int grow = rbase + r;
        if (grow < NN) {
#pragma unroll
            for (int nt = 0; nt < 4; nt++)
                h1u[(size_t)grow * HID + nt * 16 + l15] = f2bu(acc[nt][r] * dv[r]);
        }
    }
}

// ---- fused: s = sum h1'[{n}uN(n)] ; g = relu(dn*s + b1) ; h2' = dn*(g@W2) --
__global__ __launch_bounds__(256) void k_gather1f(const unsigned* __restrict__ h1u32,
                                                  const float* __restrict__ dinv,
                                                  const int* __restrict__ row_start,
                                                  const int* __restrict__ cnt,
                                                  const unsigned short* __restrict__ csr16,
                                                  const void* __restrict__ W2,
                                                  const void* __restrict__ b1,
                                                  const int* __restrict__ flags,
                                                  unsigned short* __restrict__ h2u) {
    __shared__ __align__(16) float w2t[OUTD * 68];   // [col][k], stride 68
    __shared__ __align__(16) float gbuf[8 * 68];     // [node][k], stride 68
    __shared__ float dns[8];
    const bool f32 = flags[0] != 0;
    const int t = threadIdx.x;
    for (int i = t; i < HID * OUTD; i += 256) {
        int c = i % OUTD, k = i / OUTD;
        w2t[c * 68 + k] = loadF(W2, (size_t)k * OUTD + c, f32);
    }
    const int wid = t >> 6, lane = t & 63, half = lane >> 5, l32 = lane & 31;
    const int nl = wid * 2 + half;
    const int n = blockIdx.x * 8 + nl;       // < NN (grid exact)
    const float dn = dinv[n];
    unsigned u0 = h1u32[(size_t)n * 32 + l32];
    float aL0 = bflo(u0), aH0 = bfhi(u0);    // self term (weight folded)
    float aL1 = 0.f, aH1 = 0.f, aL2 = 0.f, aH2 = 0.f, aL3 = 0.f, aH3 = 0.f;
    const int rs = row_start[n], c = cnt[n];
    for (int base = 0; base < c; base += 32) {
        int m = min(32, c - base);
        int sv = (l32 < m) ? (int)csr16[rs + base + l32] : 0;
        int j = 0;
        for (; j + 8 <= m; j += 8) {
            int s0 = __shfl(sv, j, 32),     s1 = __shfl(sv, j + 1, 32);
            int s2 = __shfl(sv, j + 2, 32), s3 = __shfl(sv, j + 3, 32);
            int s4 = __shfl(sv, j + 4, 32), s5 = __shfl(sv, j + 5, 32);
            int s6 = __shfl(sv, j + 6, 32), s7 = __shfl(sv, j + 7, 32);
            unsigned a0 = h1u32[(size_t)s0 * 32 + l32];
            unsigned a1 = h1u32[(size_t)s1 * 32 + l32];
            unsigned a2 = h1u32[(size_t)s2 * 32 + l32];
            unsigned a3 = h1u32[(size_t)s3 * 32 + l32];
            unsigned a4 = h1u32[(size_t)s4 * 32 + l32];
            unsigned a5 = h1u32[(size_t)s5 * 32 + l32];
            unsigned a6 = h1u32[(size_t)s6 * 32 + l32];
            unsigned a7 = h1u32[(size_t)s7 * 32 + l32];
            aL0 += bflo(a0); aH0 += bfhi(a0);
            aL1 += bflo(a1); aH1 += bfhi(a1);
            aL2 += bflo(a2); aH2 += bfhi(a2);
            aL3 += bflo(a3); aH3 += bfhi(a3);
            aL0 += bflo(a4); aH0 += bfhi(a4);
            aL1 += bflo(a5); aH1 += bfhi(a5);
            aL2 += bflo(a6); aH2 += bfhi(a6);
            aL3 += bflo(a7); aH3 += bfhi(a7);
        }
        for (; j < m; j++) {
            int s0 = __shfl(sv, j, 32);
            unsigned a0 = h1u32[(size_t)s0 * 32 + l32];
            aL0 += bflo(a0); aH0 += bfhi(a0);
        }
    }
    float g0 = fmaxf(dn * (aL0 + aL1 + aL2 + aL3) + loadF(b1, 2 * l32, f32), 0.f);
    float g1 = fmaxf(dn * (aH0 + aH1 + aH2 + aH3) + loadF(b1, 2 * l32 + 1, f32), 0.f);
    *(float2*)(gbuf + nl * 68 + 2 * l32) = make_float2(g0, g1);
    if (l32 == 0) dns[nl] = dn;
    __syncthreads();
    for (int idx = t; idx < 8 * OUTD; idx += 256) {
        int node = idx / OUTD, col = idx % OUTD;
        const float4* gp = (const float4*)(gbuf + node * 68);
        const float4* wp = (const float4*)(w2t + col * 68);
        float o = 0.f;
#pragma unroll 4
        for (int k4 = 0; k4 < 16; k4++) {
            float4 a = gp[k4], b = wp[k4];
            o += a.x * b.x + a.y * b.y + a.z * b.z + a.w * b.w;
        }
        h2u[(size_t)(blockIdx.x * 8 + node) * OUTD + col] = f2bu(o * dns[node]);
    }
}

// ---- CSR gather layer 2 + bias + log_softmax -------------------------------
__global__ __launch_bounds__(256) void k_gather2(const unsigned* __restrict__ h2u32,
                                                 const float* __restrict__ dinv,
                                                 const int* __restrict__ row_start,
                                                 const int* __restrict__ cnt,
                                                 const unsigned short* __restrict__ csr16,
                                                 const void* __restrict__ b2,
                                                 const int* __restrict__ flags,
                                                 void* __restrict__ out) {
    const bool f32 = flags[0] != 0;
    const int t = threadIdx.x, lane = t & 63;
    const int half = lane >> 5, l32 = lane & 31;
    const int n = blockIdx.x * 8 + (t >> 6) * 2 + half;   // < NN (grid exact)
    const bool act = l32 < (OUTD / 2);                    // 20 dwords per row
    const float dn = dinv[n];
    unsigned u0 = act ? h2u32[(size_t)n * 20 + l32] : 0u;
    float aL0 = bflo(u0), aH0 = bfhi(u0);
    float aL1 = 0.f, aH1 = 0.f, aL2 = 0.f, aH2 = 0.f, aL3 = 0.f, aH3 = 0.f;
    const int rs = row_start[n], c = cnt[n];
    for (int base = 0; base < c; base += 32) {
        int m = min(32, c - base);
        int sv = (l32 < m) ? (int)csr16[rs + base + l32] : 0;
        int j = 0;
        for (; j + 8 <= m; j += 8) {
            int s0 = __shfl(sv, j, 32),     s1 = __shfl(sv, j + 1, 32);
            int s2 = __shfl(sv, j + 2, 32), s3 = __shfl(sv, j + 3, 32);
            int s4 = __shfl(sv, j + 4, 32), s5 = __shfl(sv, j + 5, 32);
            int s6 = __shfl(sv, j + 6, 32), s7 = __shfl(sv, j + 7, 32);
            if (act) {
                unsigned a0 = h2u32[(size_t)s0 * 20 + l32];
                unsigned a1 = h2u32[(size_t)s1 * 20 + l32];
                unsigned a2 = h2u32[(size_t)s2 * 20 + l32];
                unsigned a3 = h2u32[(size_t)s3 * 20 + l32];
                unsigned a4 = h2u32[(size_t)s4 * 20 + l32];
                unsigned a5 = h2u32[(size_t)s5 * 20 + l32];
                unsigned a6 = h2u32[(size_t)s6 * 20 + l32];
                unsigned a7 = h2u32[(size_t)s7 * 20 + l32];
                aL0 += bflo(a0); aH0 += bfhi(a0);
                aL1 += bflo(a1); aH1 += bfhi(a1);
                aL2 += bflo(a2); aH2 += bfhi(a2);
                aL3 += bflo(a3); aH3 += bfhi(a3);
                aL0 += bflo(a4); aH0 += bfhi(a4);
                aL1 += bflo(a5); aH1 += bfhi(a5);
                aL2 += bflo(a6); aH2 += bfhi(a6);
                aL3 += bflo(a7); aH3 += bfhi(a7);
            }
        }
        for (; j < m; j++) {
            int s0 = __shfl(sv, j, 32);
            if (act) {
                unsigned a0 = h2u32[(size_t)s0 * 20 + l32];
                aL0 += bflo(a0); aH0 += bfhi(a0);
            }
        }
    }
    float v0 = -3.0e38f, v1 = -3.0e38f;
    if (act) {
        v0 = dn * (aL0 + aL1 + aL2 + aL3) + loadF(b2, 2 * l32, f32);
        v1 = dn * (aH0 + aH1 + aH2 + aH3) + loadF(b2, 2 * l32 + 1, f32);
    }
    float mx = fmaxf(v0, v1);
#pragma unroll
    for (int off = 16; off; off >>= 1) mx = fmaxf(mx, __shfl_xor(mx, off, 32));
    float ev = act ? expf(v0 - mx) + expf(v1 - mx) : 0.f;
#pragma unroll
    for (int off = 16; off; off >>= 1) ev += __shfl_xor(ev, off, 32);
    float lg = logf(ev);
    if (act) {
        float r0 = v0 - mx - lg, r1 = v1 - mx - lg;
        if (f32) {
            float2* p = (float2*)((float*)out + (size_t)n * OUTD + 2 * l32);
            *p = make_float2(r0, r1);
        } else {
            ((unsigned*)out)[(size_t)n * 20 + l32] = pack2bf(r0, r1);
        }
    }
}

extern "C" void kernel_launch(void* const* d_in, const int* in_sizes, int n_in,
                              void* d_out, int out_size, void* d_ws, size_t ws_size,
                              hipStream_t stream) {
    const void* x  = d_in[0];
    const int*  ei = (const int*)d_in[1];
    const void* W1 = d_in[2];
    const void* b1 = d_in[3];
    const void* W2 = d_in[4];
    const void* b2 = d_in[5];

    // ws layout (4-byte words):
    // flags[16] | dinv[50048] | cnt[50048] | cursor[50048] | row_start[50048] |
    // partial[256] | csr16 ushort[800000] | h1' bf16 [NN*64] | h2' bf16 [NN*40]
    float* ws        = (float*)d_ws;
    int*   flags     = (int*)ws;
    float* dinv      = ws + 16;
    int*   cnt       = (int*)(dinv + 50048);
    int*   cursor    = cnt + 50048;
    int*   row_start = cursor + 50048;
    int*   partial   = row_start + 50048;
    unsigned short* csr16 = (unsigned short*)(partial + 256);
    unsigned short* h1u   = csr16 + NE;
    unsigned short* h2u   = h1u + (size_t)NN * HID;

    k_zero  <<<(NN + 255) / 256, 256, 0, stream>>>((const unsigned*)x, ei, flags, cnt, cursor);
    k_hist  <<<(NE + 255) / 256, 256, 0, stream>>>(ei, flags, cnt);
    k_scan1 <<<NC, 256, 0, stream>>>(cnt, row_start, partial, dinv);
    k_scan3 <<<NC, 256, 0, stream>>>(row_start, partial);
    k_fill  <<<NCH * 8, 256, 0, stream>>>(ei, flags, row_start, cursor, csr16);
    k_gemm1 <<<(NN + 63) / 64, 256, 0, stream>>>(x, W1, dinv, flags, h1u);
    k_gather1f<<<NN / 8, 256, 0, stream>>>((const unsigned*)h1u, dinv, row_start, cnt, csr16,
                                           W2, b1, flags, h2u);
    k_gather2<<<NN / 8, 256, 0, stream>>>((const unsigned*)h2u, dinv, row_start, cnt, csr16,
                                          b2, flags, d_out);
}

// Round 9
// 237.471 us; speedup vs baseline: 3.5314x; 1.0823x over previous
//
#include <hip/hip_runtime.h>
#include <hip/hip_bf16.h>

// GCN 2-layer: N=50000 nodes, E=800000 edges, 256 -> 64 (relu) -> 40 (log_softmax)
// Float inputs fp32 or bf16 (device-detected); edges int32 or int64 (detected).
// agg[n] = dinv[n] * ( sum_{s in N(n)} h'[s] + h'[n] ), h' = h*dinv pre-scaled.
// CSR build: hist stores per-edge rank (atomic return) -> fill is atomic-free.
// Gathers: 4 nodes/wave (16-lane quarters), uint2 loads (4 bf16 cols/lane),
// 8-deep edge unroll -> 32 outstanding loads/wave.

constexpr int NN   = 50000;
constexpr int NE   = 800000;
constexpr int FEAT = 256;
constexpr int HID  = 64;
constexpr int OUTD = 40;
constexpr int NC   = (NN + 255) / 256;     // 196 scan chunks
constexpr int FCH  = 2048;                  // fill: edges per chunk
constexpr int NCH  = (NE + FCH - 1) / FCH;  // 391 chunks

typedef short bf16x8 __attribute__((ext_vector_type(8)));
typedef float f32x4  __attribute__((ext_vector_type(4)));

__device__ __forceinline__ float b2f(__hip_bfloat16 v) { return __bfloat162float(v); }
__device__ __forceinline__ float bflo(unsigned u) { return __uint_as_float(u << 16); }
__device__ __forceinline__ float bfhi(unsigned u) { return __uint_as_float(u & 0xffff0000u); }
__device__ __forceinline__ unsigned short f2bu(float f) {
    __hip_bfloat16 h = __float2bfloat16(f);
    return *(unsigned short*)&h;
}
__device__ __forceinline__ unsigned pack2bf(float a, float b) {
    return (unsigned)f2bu(a) | ((unsigned)f2bu(b) << 16);
}
__device__ __forceinline__ float loadF(const void* p, int i, bool f32) {
    return f32 ? ((const float*)p)[i] : b2f(((const __hip_bfloat16*)p)[i]);
}
__device__ __forceinline__ int loadE(const int* ei, int e, int row, bool i64) {
    long long idx = (long long)row * NE + e;
    return i64 ? ei[2 * idx] : ei[idx];
}
__device__ __forceinline__ bf16x8 pack8(float4 a, float4 b) {
    bf16x8 r;
    r[0] = (short)f2bu(a.x); r[1] = (short)f2bu(a.y);
    r[2] = (short)f2bu(a.z); r[3] = (short)f2bu(a.w);
    r[4] = (short)f2bu(b.x); r[5] = (short)f2bu(b.y);
    r[6] = (short)f2bu(b.z); r[7] = (short)f2bu(b.w);
    return r;
}

// ---- zero + dtype detection ------------------------------------------------
__global__ __launch_bounds__(256) void k_zero(const unsigned* __restrict__ xw,
                                              const int* __restrict__ ew,
                                              int* flags, int* cnt) {
    int i = blockIdx.x * 256 + threadIdx.x;
    if (i < NN) cnt[i] = 0;
    if (blockIdx.x == 0 && threadIdx.x == 0) {
        int outliers = 0;
        for (int k = 0; k < 256; k++) {
            int e = (xw[k] >> 7) & 0xFF;   // exponent of low bf16 half
            if (e < 100 || e > 140) outliers++;
        }
        flags[0] = (outliers > 64) ? 1 : 0;
        int nz = 0;
        for (int k = 1; k < 64; k += 2)
            if (ew[k] != 0) nz++;
        flags[1] = (nz == 0) ? 1 : 0;
    }
}

// ---- CSR build -------------------------------------------------------------
// hist: count in-degree AND record each edge's rank within its dst bucket.
__global__ __launch_bounds__(256) void k_hist(const int* __restrict__ ei,
                                              const int* __restrict__ flags,
                                              int* cnt, int* __restrict__ rank) {
    const bool i64 = flags[1] != 0;
    int e = blockIdx.x * 256 + threadIdx.x;
    if (e < NE) rank[e] = atomicAdd(&cnt[loadE(ei, e, 1, i64)], 1);
}
__global__ __launch_bounds__(256) void k_scan1(const int* __restrict__ cnt,
                                               int* row_start, int* partial, float* dinv) {
    __shared__ int s[256];
    int t = threadIdx.x, i = blockIdx.x * 256 + t;
    int v = (i < NN) ? cnt[i] : 0;
    if (i < NN) dinv[i] = rsqrtf(1.0f + (float)v);   // +1 self loop
    s[t] = v;
    __syncthreads();
    for (int off = 1; off < 256; off <<= 1) {
        int tmp = (t >= off) ? s[t - off] : 0;
        __syncthreads();
        s[t] += tmp;
        __syncthreads();
    }
    if (i < NN) row_start[i] = s[t] - v;
    if (t == 255) partial[blockIdx.x] = s[255];
}
__global__ __launch_bounds__(256) void k_scan3(int* row_start, const int* __restrict__ partial) {
    __shared__ int red[4];
    const int t = threadIdx.x;
    int v = (t < NC && t < (int)blockIdx.x) ? partial[t] : 0;
#pragma unroll
    for (int off = 32; off; off >>= 1) v += __shfl_xor(v, off, 64);
    if ((t & 63) == 0) red[t >> 6] = v;
    __syncthreads();
    int total = red[0] + red[1] + red[2] + red[3];
    int i = blockIdx.x * 256 + t;
    if (i < NN) row_start[i] += total;
}
// Atomic-free fill; 8 blocks per chunk, class = dst/6250 for XCD write locality.
__global__ __launch_bounds__(256) void k_fill(const int* __restrict__ ei,
                                              const int* __restrict__ flags,
                                              const int* __restrict__ row_start,
                                              const int* __restrict__ rank,
                                              unsigned short* __restrict__ csr16) {
    const bool i64 = flags[1] != 0;
    const int cls = blockIdx.x & 7;
    const int e0 = (blockIdx.x >> 3) * FCH;
#pragma unroll
    for (int k = 0; k < FCH / 256; k++) {
        int e = e0 + k * 256 + threadIdx.x;
        if (e < NE) {
            int d = loadE(ei, e, 1, i64);
            if (d / 6250 == cls) {
                int s = loadE(ei, e, 0, i64);
                csr16[row_start[d] + rank[e]] = (unsigned short)s;
            }
        }
    }
}

// ---- layer 1 GEMM (MFMA): h1' = (x @ W1) * dinv[row]  (bf16 out) -----------
__global__ __launch_bounds__(256) void k_gemm1(const void* __restrict__ xb,
                                               const void* __restrict__ W1,
                                               const float* __restrict__ dinv,
                                               const int* __restrict__ flags,
                                               unsigned short* __restrict__ h1u) {
    __shared__ __align__(16) unsigned short wt16[64 * 264];
    const bool f32 = flags[0] != 0;
    const int t = threadIdx.x;
    if (f32) {
        const float* wf = (const float*)W1;
        for (int i = t * 4; i < FEAT * HID; i += 1024) {
            float4 w = *(const float4*)(wf + i);
            int k = i >> 6, n0 = i & 63;
            wt16[(n0 + 0) * 264 + k] = f2bu(w.x);
            wt16[(n0 + 1) * 264 + k] = f2bu(w.y);
            wt16[(n0 + 2) * 264 + k] = f2bu(w.z);
            wt16[(n0 + 3) * 264 + k] = f2bu(w.w);
        }
    } else {
        const unsigned short* wu = (const unsigned short*)W1;
        for (int i = t * 4; i < FEAT * HID; i += 1024) {
            ushort4 w = *(const ushort4*)(wu + i);
            int k = i >> 6, n0 = i & 63;
            wt16[(n0 + 0) * 264 + k] = w.x;
            wt16[(n0 + 1) * 264 + k] = w.y;
            wt16[(n0 + 2) * 264 + k] = w.z;
            wt16[(n0 + 3) * 264 + k] = w.w;
        }
    }
    const int wv = t >> 6, lane = t & 63, l15 = lane & 15, quad = lane >> 4;
    const int gr = blockIdx.x * 64 + wv * 16 + l15;
    const bool rowok = gr < NN;
    f32x4 acc[4];
#pragma unroll
    for (int nt = 0; nt < 4; nt++) acc[nt] = (f32x4){0.f, 0.f, 0.f, 0.f};
    __syncthreads();

    if (f32) {
        const float* xr = (const float*)xb + (size_t)gr * FEAT + quad * 8;
        float4 z4 = make_float4(0, 0, 0, 0);
        float4 c0 = rowok ? *(const float4*)xr : z4;
        float4 c1 = rowok ? *(const float4*)(xr + 4) : z4;
#pragma unroll
        for (int ks = 0; ks < 8; ks++) {
            float4 n0 = z4, n1 = z4;
            if (ks < 7 && rowok) {
                n0 = *(const float4*)(xr + (ks + 1) * 32);
                n1 = *(const float4*)(xr + (ks + 1) * 32 + 4);
            }
            bf16x8 a = pack8(c0, c1);
            const unsigned short* wk = wt16 + ks * 32 + quad * 8;
#pragma unroll
            for (int nt = 0; nt < 4; nt++) {
                bf16x8 b = *(const bf16x8*)(wk + (size_t)(nt * 16 + l15) * 264);
                acc[nt] = __builtin_amdgcn_mfma_f32_16x16x32_bf16(a, b, acc[nt], 0, 0, 0);
            }
            c0 = n0; c1 = n1;
        }
    } else {
        const unsigned short* xr = (const unsigned short*)xb + (size_t)gr * FEAT + quad * 8;
        bf16x8 zz = (bf16x8){0, 0, 0, 0, 0, 0, 0, 0};
        bf16x8 cur = rowok ? *(const bf16x8*)xr : zz;
#pragma unroll
        for (int ks = 0; ks < 8; ks++) {
            bf16x8 nxt = zz;
            if (ks < 7 && rowok) nxt = *(const bf16x8*)(xr + (ks + 1) * 32);
            const unsigned short* wk = wt16 + ks * 32 + quad * 8;
#pragma unroll
            for (int nt = 0; nt < 4; nt++) {
                bf16x8 b = *(const bf16x8*)(wk + (size_t)(nt * 16 + l15) * 264);
                acc[nt] = __builtin_amdgcn_mfma_f32_16x16x32_bf16(cur, b, acc[nt], 0, 0, 0);
            }
            cur = nxt;
        }
    }
    const int rbase = blockIdx.x * 64 + wv * 16 + quad * 4;
    float dv[4];
#pragma unroll
    for (int r = 0; r < 4; r++) dv[r] = (rbase + r < NN) ? dinv[rbase + r] : 0.f;
#pragma unroll
    for (int r = 0; r < 4; r++) {
        int grow = rbase + r;
        if (grow < NN) {
#pragma unroll
            for (int nt = 0; nt < 4; nt++)
                h1u[(size_t)grow * HID + nt * 16 + l15] = f2bu(acc[nt][r] * dv[r]);
        }
    }
}

// ---- fused: s = sum h1'[{n}uN(n)] ; g = relu(dn*s + b1) ; h2' = dn*(g@W2) --
// 4 nodes/wave (16-lane quarters); lane = 4 cols (uint2); 8-deep unroll.
// Grid = NN/16 = 3125 exactly.
__global__ __launch_bounds__(256) void k_gather1f(const uint2* __restrict__ h1v,
                                                  const float* __restrict__ dinv,
                                                  const int* __restrict__ row_start,
                                                  const int* __restrict__ cnt,
                                                  const unsigned short* __restrict__ csr16,
                                                  const void* __restrict__ W2,
                                                  const void* __restrict__ b1,
                                                  const int* __restrict__ flags,
                                                  unsigned short* __restrict__ h2u) {
    __shared__ __align__(16) float w2t[OUTD * 68];   // [col][k], stride 68
    __shared__ __align__(16) float gbuf[16 * 68];    // [node][k], stride 68
    __shared__ float dns[16];
    const bool f32 = flags[0] != 0;
    const int t = threadIdx.x;
    // stage W2^T, k-major (consecutive t -> consecutive k -> conflict-free)
    for (int i = t; i < HID * OUTD; i += 256) {
        int c = i >> 6, k = i & 63;
        w2t[c * 68 + k] = loadF(W2, (size_t)k * OUTD + c, f32);
    }
    const int nl = t >> 4, l16 = t & 15;
    const int n = blockIdx.x * 16 + nl;      // < NN (grid exact)
    const float dn = dinv[n];
    uint2 u0 = h1v[(size_t)n * 16 + l16];    // cols 4*l16 .. 4*l16+3
    float a00 = bflo(u0.x), a01 = bfhi(u0.x), a02 = bflo(u0.y), a03 = bfhi(u0.y);
    float a10 = 0.f, a11 = 0.f, a12 = 0.f, a13 = 0.f;
    float a20 = 0.f, a21 = 0.f, a22 = 0.f, a23 = 0.f;
    float a30 = 0.f, a31 = 0.f, a32 = 0.f, a33 = 0.f;
    const int rs = row_start[n], c = cnt[n];
    for (int base = 0; base < c; base += 16) {
        int m = min(16, c - base);
        int sv = (l16 < m) ? (int)csr16[rs + base + l16] : 0;
        int j = 0;
        for (; j + 8 <= m; j += 8) {
            int s0 = __shfl(sv, j, 16),     s1 = __shfl(sv, j + 1, 16);
            int s2 = __shfl(sv, j + 2, 16), s3 = __shfl(sv, j + 3, 16);
            int s4 = __shfl(sv, j + 4, 16), s5 = __shfl(sv, j + 5, 16);
            int s6 = __shfl(sv, j + 6, 16), s7 = __shfl(sv, j + 7, 16);
            uint2 b0 = h1v[(size_t)s0 * 16 + l16];
            uint2 b1v_ = h1v[(size_t)s1 * 16 + l16];
            uint2 b2v = h1v[(size_t)s2 * 16 + l16];
            uint2 b3 = h1v[(size_t)s3 * 16 + l16];
            uint2 b4 = h1v[(size_t)s4 * 16 + l16];
            uint2 b5 = h1v[(size_t)s5 * 16 + l16];
            uint2 b6 = h1v[(size_t)s6 * 16 + l16];
            uint2 b7 = h1v[(size_t)s7 * 16 + l16];
            a00 += bflo(b0.x); a01 += bfhi(b0.x); a02 += bflo(b0.y); a03 += bfhi(b0.y);
            a10 += bflo(b1v_.x); a11 += bfhi(b1v_.x); a12 += bflo(b1v_.y); a13 += bfhi(b1v_.y);
            a20 += bflo(b2v.x); a21 += bfhi(b2v.x); a22 += bflo(b2v.y); a23 += bfhi(b2v.y);
            a30 += bflo(b3.x); a31 += bfhi(b3.x); a32 += bflo(b3.y); a33 += bfhi(b3.y);
            a00 += bflo(b4.x); a01 += bfhi(b4.x); a02 += bflo(b4.y); a03 += bfhi(b4.y);
            a10 += bflo(b5.x); a11 += bfhi(b5.x); a12 += bflo(b5.y); a13 += bfhi(b5.y);
            a20 += bflo(b6.x); a21 += bfhi(b6.x); a22 += bflo(b6.y); a23 += bfhi(b6.y);
            a30 += bflo(b7.x); a31 += bfhi(b7.x); a32 += bflo(b7.y); a33 += bfhi(b7.y);
        }
        for (; j < m; j++) {
            int s0 = __shfl(sv, j, 16);
            uint2 b0 = h1v[(size_t)s0 * 16 + l16];
            a00 += bflo(b0.x); a01 += bfhi(b0.x); a02 += bflo(b0.y); a03 += bfhi(b0.y);
        }
    }
    int cb = 4 * l16;
    float g0 = fmaxf(dn * (a00 + a10 + a20 + a30) + loadF(b1, cb, f32), 0.f);
    float g1 = fmaxf(dn * (a01 + a11 + a21 + a31) + loadF(b1, cb + 1, f32), 0.f);
    float g2 = fmaxf(dn * (a02 + a12 + a22 + a32) + loadF(b1, cb + 2, f32), 0.f);
    float g3 = fmaxf(dn * (a03 + a13 + a23 + a33) + loadF(b1, cb + 3, f32), 0.f);
    *(float4*)(gbuf + nl * 68 + cb) = make_float4(g0, g1, g2, g3);
    if (l16 == 0) dns[nl] = dn;
    __syncthreads();
    // matvec: h2'[node][col] = dns[node] * sum_k g[k]*W2[k][col]; 640 outputs
    for (int idx = t; idx < 16 * OUTD; idx += 256) {
        int node = idx / OUTD, col = idx % OUTD;
        const float4* gp = (const float4*)(gbuf + node * 68);
        const float4* wp = (const float4*)(w2t + col * 68);
        float o = 0.f;
#pragma unroll 4
        for (int k4 = 0; k4 < 16; k4++) {
            float4 a = gp[k4], b = wp[k4];
            o += a.x * b.x + a.y * b.y + a.z * b.z + a.w * b.w;
        }
        h2u[(size_t)(blockIdx.x * 16 + node) * OUTD + col] = f2bu(o * dns[node]);
    }
}

// ---- CSR gather layer 2 + bias + log_softmax -------------------------------
// 4 nodes/wave; 10 active lanes per quarter (20 dwords/row as uint2).
__global__ __launch_bounds__(256) void k_gather2(const uint2* __restrict__ h2v,
                                                 const float* __restrict__ dinv,
                                                 const int* __restrict__ row_start,
                                                 const int* __restrict__ cnt,
                                                 const unsigned short* __restrict__ csr16,
                                                 const void* __restrict__ b2,
                                                 const int* __restrict__ flags,
                                                 void* __restrict__ out) {
    const bool f32 = flags[0] != 0;
    const int t = threadIdx.x;
    const int nl = t >> 4, l16 = t & 15;
    const int n = blockIdx.x * 16 + nl;      // < NN (grid exact)
    const bool act = l16 < 10;               // 10 uint2 per row
    const float dn = dinv[n];
    uint2 u0 = act ? h2v[(size_t)n * 10 + l16] : make_uint2(0, 0);
    float a00 = bflo(u0.x), a01 = bfhi(u0.x), a02 = bflo(u0.y), a03 = bfhi(u0.y);
    float a10 = 0.f, a11 = 0.f, a12 = 0.f, a13 = 0.f;
    float a20 = 0.f, a21 = 0.f, a22 = 0.f, a23 = 0.f;
    float a30 = 0.f, a31 = 0.f, a32 = 0.f, a33 = 0.f;
    const int rs = row_start[n], c = cnt[n];
    for (int base = 0; base < c; base += 16) {
        int m = min(16, c - base);
        int sv = (l16 < m) ? (int)csr16[rs + base + l16] : 0;
        int j = 0;
        for (; j + 8 <= m; j += 8) {
            int s0 = __shfl(sv, j, 16),     s1 = __shfl(sv, j + 1, 16);
            int s2 = __shfl(sv, j + 2, 16), s3 = __shfl(sv, j + 3, 16);
            int s4 = __shfl(sv, j + 4, 16), s5 = __shfl(sv, j + 5, 16);
            int s6 = __shfl(sv, j + 6, 16), s7 = __shfl(sv, j + 7, 16);
            if (act) {
                uint2 b0 = h2v[(size_t)s0 * 10 + l16];
                uint2 b1v_ = h2v[(size_t)s1 * 10 + l16];
                uint2 b2v = h2v[(size_t)s2 * 10 + l16];
                uint2 b3 = h2v[(size_t)s3 * 10 + l16];
                uint2 b4 = h2v[(size_t)s4 * 10 + l16];
                uint2 b5 = h2v[(size_t)s5 * 10 + l16];
                uint2 b6 = h2v[(size_t)s6 * 10 + l16];
                uint2 b7 = h2v[(size_t)s7 * 10 + l16];
                a00 += bflo(b0.x); a01 += bfhi(b0.x); a02 += bflo(b0.y); a03 += bfhi(b0.y);
                a10 += bflo(b1v_.x); a11 += bfhi(b1v_.x); a12 += bflo(b1v_.y); a13 += bfhi(b1v_.y);
                a20 += bflo(b2v.x); a21 += bfhi(b2v.x); a22 += bflo(b2v.y); a23 += bfhi(b2v.y);
                a30 += bflo(b3.x); a31 += bfhi(b3.x); a32 += bflo(b3.y); a33 += bfhi(b3.y);
                a00 += bflo(b4.x); a01 += bfhi(b4.x); a02 += bflo(b4.y); a03 += bfhi(b4.y);
                a10 += bflo(b5.x); a11 += bfhi(b5.x); a12 += bflo(b5.y); a13 += bfhi(b5.y);
                a20 += bflo(b6.x); a21 += bfhi(b6.x); a22 += bflo(b6.y); a23 += bfhi(b6.y);
                a30 += bflo(b7.x); a31 += bfhi(b7.x); a32 += bflo(b7.y); a33 += bfhi(b7.y);
            }
        }
        for (; j < m; j++) {
            int s0 = __shfl(sv, j, 16);
            if (act) {
                uint2 b0 = h2v[(size_t)s0 * 10 + l16];
                a00 += bflo(b0.x); a01 += bfhi(b0.x); a02 += bflo(b0.y); a03 += bfhi(b0.y);
            }
        }
    }
    int cb = 4 * l16;
    float v0 = -3.0e38f, v1 = -3.0e38f, v2 = -3.0e38f, v3 = -3.0e38f;
    if (act) {
        v0 = dn * (a00 + a10 + a20 + a30) + loadF(b2, cb, f32);
        v1 = dn * (a01 + a11 + a21 + a31) + loadF(b2, cb + 1, f32);
        v2 = dn * (a02 + a12 + a22 + a32) + loadF(b2, cb + 2, f32);
        v3 = dn * (a03 + a13 + a23 + a33) + loadF(b2, cb + 3, f32);
    }
    float mx = fmaxf(fmaxf(v0, v1), fmaxf(v2, v3));
#pragma unroll
    for (int off = 8; off; off >>= 1) mx = fmaxf(mx, __shfl_xor(mx, off, 16));
    float ev = act ? expf(v0 - mx) + expf(v1 - mx) + expf(v2 - mx) + expf(v3 - mx) : 0.f;
#pragma unroll
    for (int off = 8; off; off >>= 1) ev += __shfl_xor(ev, off, 16);
    float lg = logf(ev);
    if (act) {
        float r0 = v0 - mx - lg, r1 = v1 - mx - lg;
        float r2 = v2 - mx - lg, r3 = v3 - mx - lg;
        if (f32) {
            *(float4*)((float*)out + (size_t)n * OUTD + cb) = make_float4(r0, r1, r2, r3);
        } else {
            ((uint2*)out)[(size_t)n * 10 + l16] = make_uint2(pack2bf(r0, r1), pack2bf(r2, r3));
        }
    }
}

extern "C" void kernel_launch(void* const* d_in, const int* in_sizes, int n_in,
                              void* d_out, int out_size, void* d_ws, size_t ws_size,
                              hipStream_t stream) {
    const void* x  = d_in[0];
    const int*  ei = (const int*)d_in[1];
    const void* W1 = d_in[2];
    const void* b1 = d_in[3];
    const void* W2 = d_in[4];
    const void* b2 = d_in[5];

    // ws layout (4-byte words):
    // flags[16] | dinv[50048] | cnt[50048] | row_start[50048] | partial[256] |
    // rank[800000] | csr16 ushort[800000] | h1' bf16 [NN*64] | h2' bf16 [NN*40]
    float* ws        = (float*)d_ws;
    int*   flags     = (int*)ws;
    float* dinv      = ws + 16;
    int*   cnt       = (int*)(dinv + 50048);
    int*   row_start = cnt + 50048;
    int*   partial   = row_start + 50048;
    int*   rank      = partial + 256;
    unsigned short* csr16 = (unsigned short*)(rank + NE);
    unsigned short* h1u   = csr16 + NE;
    unsigned short* h2u   = h1u + (size_t)NN * HID;

    k_zero  <<<(NN + 255) / 256, 256, 0, stream>>>((const unsigned*)x, ei, flags, cnt);
    k_hist  <<<(NE + 255) / 256, 256, 0, stream>>>(ei, flags, cnt, rank);
    k_scan1 <<<NC, 256, 0, stream>>>(cnt, row_start, partial, dinv);
    k_scan3 <<<NC, 256, 0, stream>>>(row_start, partial);
    k_fill  <<<NCH * 8, 256, 0, stream>>>(ei, flags, row_start, rank, csr16);
    k_gemm1 <<<(NN + 63) / 64, 256, 0, stream>>>(x, W1, dinv, flags, h1u);
    k_gather1f<<<NN / 16, 256, 0, stream>>>((const uint2*)h1u, dinv, row_start, cnt, csr16,
                                            W2, b1, flags, h2u);
    k_gather2<<<NN / 16, 256, 0, stream>>>((const uint2*)h2u, dinv, row_start, cnt, csr16,
                                           b2, flags, d_out);
}

// Round 10
// 230.110 us; speedup vs baseline: 3.6443x; 1.0320x over previous
//
#include <hip/hip_runtime.h>
#include <hip/hip_bf16.h>

// GCN 2-layer: N=50000 nodes, E=800000 edges, 256 -> 64 (relu) -> 40 (log_softmax)
// Float inputs fp32 or bf16 (device-detected); edges int32 or int64 (detected).
// agg[n] = dinv[n] * ( sum_{s in N(n)} h'[s] + h'[n] ), h' = h*dinv pre-scaled.
// CSR: hist records per-edge rank -> atomic-free fill. Gathers: 4 nodes/wave
// (16-lane quarters), uint2 loads, BRANCH-FREE 16-deep batches padded with a
// zero row at index 50000 (no serial tail).

constexpr int NN   = 50000;
constexpr int NNP  = 50048;                 // padded row count (zero rows >= NN)
constexpr int ZR   = 50000;                 // zero-row index for padding lanes
constexpr int NE   = 800000;
constexpr int FEAT = 256;
constexpr int HID  = 64;
constexpr int OUTD = 40;
constexpr int NC   = (NN + 255) / 256;     // 196 scan chunks
constexpr int FCH  = 2048;                  // fill: edges per chunk
constexpr int NCH  = (NE + FCH - 1) / FCH;  // 391 chunks

typedef short bf16x8 __attribute__((ext_vector_type(8)));
typedef float f32x4  __attribute__((ext_vector_type(4)));

__device__ __forceinline__ float b2f(__hip_bfloat16 v) { return __bfloat162float(v); }
__device__ __forceinline__ float bflo(unsigned u) { return __uint_as_float(u << 16); }
__device__ __forceinline__ float bfhi(unsigned u) { return __uint_as_float(u & 0xffff0000u); }
__device__ __forceinline__ unsigned short f2bu(float f) {
    __hip_bfloat16 h = __float2bfloat16(f);
    return *(unsigned short*)&h;
}
__device__ __forceinline__ unsigned pack2bf(float a, float b) {
    return (unsigned)f2bu(a) | ((unsigned)f2bu(b) << 16);
}
__device__ __forceinline__ float loadF(const void* p, int i, bool f32) {
    return f32 ? ((const float*)p)[i] : b2f(((const __hip_bfloat16*)p)[i]);
}
__device__ __forceinline__ int loadE(const int* ei, int e, int row, bool i64) {
    long long idx = (long long)row * NE + e;
    return i64 ? ei[2 * idx] : ei[idx];
}
__device__ __forceinline__ bf16x8 pack8(float4 a, float4 b) {
    bf16x8 r;
    r[0] = (short)f2bu(a.x); r[1] = (short)f2bu(a.y);
    r[2] = (short)f2bu(a.z); r[3] = (short)f2bu(a.w);
    r[4] = (short)f2bu(b.x); r[5] = (short)f2bu(b.y);
    r[6] = (short)f2bu(b.z); r[7] = (short)f2bu(b.w);
    return r;
}

// ---- zero + dtype detection + h2 pad-row zero ------------------------------
__global__ __launch_bounds__(256) void k_zero(const unsigned* __restrict__ xw,
                                              const int* __restrict__ ew,
                                              int* flags, int* cnt,
                                              unsigned* __restrict__ h2pad) {
    int i = blockIdx.x * 256 + threadIdx.x;
    if (i < NN) cnt[i] = 0;
    if (blockIdx.x == 0 && threadIdx.x < 20) h2pad[threadIdx.x] = 0;  // h2 zero row
    if (blockIdx.x == 0 && threadIdx.x == 0) {
        int outliers = 0;
        for (int k = 0; k < 256; k++) {
            int e = (xw[k] >> 7) & 0xFF;   // exponent of low bf16 half
            if (e < 100 || e > 140) outliers++;
        }
        flags[0] = (outliers > 64) ? 1 : 0;
        int nz = 0;
        for (int k = 1; k < 64; k += 2)
            if (ew[k] != 0) nz++;
        flags[1] = (nz == 0) ? 1 : 0;
    }
}

// ---- CSR build -------------------------------------------------------------
__global__ __launch_bounds__(256) void k_hist(const int* __restrict__ ei,
                                              const int* __restrict__ flags,
                                              int* cnt, int* __restrict__ rank) {
    const bool i64 = flags[1] != 0;
    int e = blockIdx.x * 256 + threadIdx.x;
    if (e < NE) rank[e] = atomicAdd(&cnt[loadE(ei, e, 1, i64)], 1);
}
__global__ __launch_bounds__(256) void k_scan1(const int* __restrict__ cnt,
                                               int* row_start, int* partial, float* dinv) {
    __shared__ int s[256];
    int t = threadIdx.x, i = blockIdx.x * 256 + t;
    int v = (i < NN) ? cnt[i] : 0;
    if (i < NN) dinv[i] = rsqrtf(1.0f + (float)v);   // +1 self loop
    s[t] = v;
    __syncthreads();
    for (int off = 1; off < 256; off <<= 1) {
        int tmp = (t >= off) ? s[t - off] : 0;
        __syncthreads();
        s[t] += tmp;
        __syncthreads();
    }
    if (i < NN) row_start[i] = s[t] - v;       // exclusive within chunk
    if (t == 255) partial[blockIdx.x] = s[255];
}
// single block: pp[c] = exclusive prefix of partial[0..NC)
__global__ __launch_bounds__(256) void k_scan2p(const int* __restrict__ partial, int* pp) {
    __shared__ int s[256];
    int t = threadIdx.x;
    int v = (t < NC) ? partial[t] : 0;
    s[t] = v;
    __syncthreads();
    for (int off = 1; off < 256; off <<= 1) {
        int tmp = (t >= off) ? s[t - off] : 0;
        __syncthreads();
        s[t] += tmp;
        __syncthreads();
    }
    pp[t] = s[t] - v;
}
// Atomic-free fill; 8 blocks per chunk, class = dst/6250 for XCD write locality.
__global__ __launch_bounds__(256) void k_fill(const int* __restrict__ ei,
                                              const int* __restrict__ flags,
                                              const int* __restrict__ row_start,
                                              const int* __restrict__ pp,
                                              const int* __restrict__ rank,
                                              unsigned short* __restrict__ csr16) {
    const bool i64 = flags[1] != 0;
    const int cls = blockIdx.x & 7;
    const int e0 = (blockIdx.x >> 3) * FCH;
#pragma unroll
    for (int k = 0; k < FCH / 256; k++) {
        int e = e0 + k * 256 + threadIdx.x;
        if (e < NE) {
            int d = loadE(ei, e, 1, i64);
            if (d / 6250 == cls) {
                int s = loadE(ei, e, 0, i64);
                csr16[row_start[d] + pp[d >> 8] + rank[e]] = (unsigned short)s;
            }
        }
    }
}

// ---- layer 1 GEMM (MFMA): h1' = (x @ W1) * dinv[row]; zero rows >= NN ------
__global__ __launch_bounds__(256) void k_gemm1(const void* __restrict__ xb,
                                               const void* __restrict__ W1,
                                               const float* __restrict__ dinv,
                                               const int* __restrict__ flags,
                                               unsigned short* __restrict__ h1u) {
    __shared__ __align__(16) unsigned short wt16[64 * 264];
    const bool f32 = flags[0] != 0;
    const int t = threadIdx.x;
    if (f32) {
        const float* wf = (const float*)W1;
        for (int i = t * 4; i < FEAT * HID; i += 1024) {
            float4 w = *(const float4*)(wf + i);
            int k = i >> 6, n0 = i & 63;
            wt16[(n0 + 0) * 264 + k] = f2bu(w.x);
            wt16[(n0 + 1) * 264 + k] = f2bu(w.y);
            wt16[(n0 + 2) * 264 + k] = f2bu(w.z);
            wt16[(n0 + 3) * 264 + k] = f2bu(w.w);
        }
    } else {
        const unsigned short* wu = (const unsigned short*)W1;
        for (int i = t * 4; i < FEAT * HID; i += 1024) {
            ushort4 w = *(const ushort4*)(wu + i);
            int k = i >> 6, n0 = i & 63;
            wt16[(n0 + 0) * 264 + k] = w.x;
            wt16[(n0 + 1) * 264 + k] = w.y;
            wt16[(n0 + 2) * 264 + k] = w.z;
            wt16[(n0 + 3) * 264 + k] = w.w;
        }
    }
    const int wv = t >> 6, lane = t & 63, l15 = lane & 15, quad = lane >> 4;
    const int gr = blockIdx.x * 64 + wv * 16 + l15;
    const bool rowok = gr < NN;
    f32x4 acc[4];
#pragma unroll
    for (int nt = 0; nt < 4; nt++) acc[nt] = (f32x4){0.f, 0.f, 0.f, 0.f};
    __syncthreads();

    if (f32) {
        const float* xr = (const float*)xb + (size_t)gr * FEAT + quad * 8;
        float4 z4 = make_float4(0, 0, 0, 0);
        float4 c0 = rowok ? *(const float4*)xr : z4;
        float4 c1 = rowok ? *(const float4*)(xr + 4) : z4;
#pragma unroll
        for (int ks = 0; ks < 8; ks++) {
            float4 n0 = z4, n1 = z4;
            if (ks < 7 && rowok) {
                n0 = *(const float4*)(xr + (ks + 1) * 32);
                n1 = *(const float4*)(xr + (ks + 1) * 32 + 4);
            }
            bf16x8 a = pack8(c0, c1);
            const unsigned short* wk = wt16 + ks * 32 + quad * 8;
#pragma unroll
            for (int nt = 0; nt < 4; nt++) {
                bf16x8 b = *(const bf16x8*)(wk + (size_t)(nt * 16 + l15) * 264);
                acc[nt] = __builtin_amdgcn_mfma_f32_16x16x32_bf16(a, b, acc[nt], 0, 0, 0);
            }
            c0 = n0; c1 = n1;
        }
    } else {
        const unsigned short* xr = (const unsigned short*)xb + (size_t)gr * FEAT + quad * 8;
        bf16x8 zz = (bf16x8){0, 0, 0, 0, 0, 0, 0, 0};
        bf16x8 cur = rowok ? *(const bf16x8*)xr : zz;
#pragma unroll
        for (int ks = 0; ks < 8; ks++) {
            bf16x8 nxt = zz;
            if (ks < 7 && rowok) nxt = *(const bf16x8*)(xr + (ks + 1) * 32);
            const unsigned short* wk = wt16 + ks * 32 + quad * 8;
#pragma unroll
            for (int nt = 0; nt < 4; nt++) {
                bf16x8 b = *(const bf16x8*)(wk + (size_t)(nt * 16 + l15) * 264);
                acc[nt] = __builtin_amdgcn_mfma_f32_16x16x32_bf16(cur, b, acc[nt], 0, 0, 0);
            }
            cur = nxt;
        }
    }
    const int rbase = blockIdx.x * 64 + wv * 16 + quad * 4;
    float dv[4];
#pragma unroll
    for (int r = 0; r < 4; r++) dv[r] = (rbase + r < NN) ? dinv[rbase + r] : 0.f;
#pragma unroll
    for (int r = 0; r < 4; r++) {
        int grow = rbase + r;   // < NNP always (grid covers 50048 rows)
#pragma unroll
        for (int nt = 0; nt < 4; nt++)
            h1u[(size_t)grow * HID + nt * 16 + l15] = f2bu(acc[nt][r] * dv[r]);
    }
}

// ---- fused: s = sum h1'[{n}uN(n)] ; g = relu(dn*s + b1) ; h2' = dn*(g@W2) --
// 4 nodes/wave, uint2/lane, branch-free 16-deep batches (zero-row padded).
__global__ __launch_bounds__(256) void k_gather1f(const uint2* __restrict__ h1v,
                                                  const float* __restrict__ dinv,
                                                  const int* __restrict__ row_start,
                                                  const int* __restrict__ pp,
                                                  const int* __restrict__ cnt,
                                                  const unsigned short* __restrict__ csr16,
                                                  const void* __restrict__ W2,
                                                  const void* __restrict__ b1,
                                                  const int* __restrict__ flags,
                                                  unsigned short* __restrict__ h2u) {
    __shared__ __align__(16) float w2t[OUTD * 68];   // [col][k], stride 68
    __shared__ __align__(16) float gbuf[16 * 68];    // [node][k], stride 68
    __shared__ float dns[16];
    const bool f32 = flags[0] != 0;
    const int t = threadIdx.x;
    for (int i = t; i < HID * OUTD; i += 256) {
        int c = i >> 6, k = i & 63;
        w2t[c * 68 + k] = loadF(W2, (size_t)k * OUTD + c, f32);
    }
    const int nl = t >> 4, l16 = t & 15;
    const int n = blockIdx.x * 16 + nl;      // < NN (grid exact)
    const float dn = dinv[n];
    uint2 u0 = h1v[(size_t)n * 16 + l16];
    float a0 = bflo(u0.x), a1 = bfhi(u0.x), a2 = bflo(u0.y), a3 = bfhi(u0.y);
    float e0 = 0.f, e1 = 0.f, e2 = 0.f, e3 = 0.f;
    const int rs = row_start[n] + pp[n >> 8], c = cnt[n];
    for (int base = 0; base < c; base += 16) {
        int rem = c - base;
        int sv = (l16 < rem) ? (int)csr16[rs + base + l16] : ZR;
        uint2 b[8], d[8];
#pragma unroll
        for (int j = 0; j < 8; j++) {
            int s = __shfl(sv, j, 16);
            b[j] = h1v[(size_t)s * 16 + l16];
        }
#pragma unroll
        for (int j = 0; j < 8; j++) {
            int s = __shfl(sv, j + 8, 16);
            d[j] = h1v[(size_t)s * 16 + l16];
        }
#pragma unroll
        for (int j = 0; j < 8; j++) {
            a0 += bflo(b[j].x); a1 += bfhi(b[j].x);
            a2 += bflo(b[j].y); a3 += bfhi(b[j].y);
            e0 += bflo(d[j].x); e1 += bfhi(d[j].x);
            e2 += bflo(d[j].y); e3 += bfhi(d[j].y);
        }
    }
    int cb = 4 * l16;
    float g0 = fmaxf(dn * (a0 + e0) + loadF(b1, cb, f32), 0.f);
    float g1 = fmaxf(dn * (a1 + e1) + loadF(b1, cb + 1, f32), 0.f);
    float g2 = fmaxf(dn * (a2 + e2) + loadF(b1, cb + 2, f32), 0.f);
    float g3 = fmaxf(dn * (a3 + e3) + loadF(b1, cb + 3, f32), 0.f);
    *(float4*)(gbuf + nl * 68 + cb) = make_float4(g0, g1, g2, g3);
    if (l16 == 0) dns[nl] = dn;
    __syncthreads();
    for (int idx = t; idx < 16 * OUTD; idx += 256) {
        int node = idx / OUTD, col = idx % OUTD;
        const float4* gp = (const float4*)(gbuf + node * 68);
        const float4* wp = (const float4*)(w2t + col * 68);
        float o = 0.f;
#pragma unroll 4
        for (int k4 = 0; k4 < 16; k4++) {
            float4 a = gp[k4], b = wp[k4];
            o += a.x * b.x + a.y * b.y + a.z * b.z + a.w * b.w;
        }
        h2u[(size_t)(blockIdx.x * 16 + node) * OUTD + col] = f2bu(o * dns[node]);
    }
}

// ---- CSR gather layer 2 + bias + log_softmax (branch-free 16-deep) ---------
__global__ __launch_bounds__(256) void k_gather2(const uint2* __restrict__ h2v,
                                                 const float* __restrict__ dinv,
                                                 const int* __restrict__ row_start,
                                                 const int* __restrict__ pp,
                                                 const int* __restrict__ cnt,
                                                 const unsigned short* __restrict__ csr16,
                                                 const void* __restrict__ b2,
                                                 const int* __restrict__ flags,
                                                 void* __restrict__ out) {
    const bool f32 = flags[0] != 0;
    const int t = threadIdx.x;
    const int nl = t >> 4, l16 = t & 15;
    const int n = blockIdx.x * 16 + nl;      // < NN (grid exact)
    const bool act = l16 < 10;               // 10 uint2 per 40-col row
    const float dn = dinv[n];
    const int lclamp = act ? l16 : 9;        // inactive lanes read lane-9 slot (discarded)
    uint2 u0 = h2v[(size_t)n * 10 + lclamp];
    float a0 = bflo(u0.x), a1 = bfhi(u0.x), a2 = bflo(u0.y), a3 = bfhi(u0.y);
    float e0 = 0.f, e1 = 0.f, e2 = 0.f, e3 = 0.f;
    const int rs = row_start[n] + pp[n >> 8], c = cnt[n];
    for (int base = 0; base < c; base += 16) {
        int rem = c - base;
        int sv = (l16 < rem) ? (int)csr16[rs + base + l16] : ZR;
        uint2 b[8], d[8];
#pragma unroll
        for (int j = 0; j < 8; j++) {
            int s = __shfl(sv, j, 16);
            b[j] = h2v[(size_t)s * 10 + lclamp];
        }
#pragma unroll
        for (int j = 0; j < 8; j++) {
            int s = __shfl(sv, j + 8, 16);
            d[j] = h2v[(size_t)s * 10 + lclamp];
        }
#pragma unroll
        for (int j = 0; j < 8; j++) {
            a0 += bflo(b[j].x); a1 += bfhi(b[j].x);
            a2 += bflo(b[j].y); a3 += bfhi(b[j].y);
            e0 += bflo(d[j].x); e1 += bfhi(d[j].x);
            e2 += bflo(d[j].y); e3 += bfhi(d[j].y);
        }
    }
    int cb = 4 * l16;
    float v0 = -3.0e38f, v1 = -3.0e38f, v2 = -3.0e38f, v3 = -3.0e38f;
    if (act) {
        v0 = dn * (a0 + e0) + loadF(b2, cb, f32);
        v1 = dn * (a1 + e1) + loadF(b2, cb + 1, f32);
        v2 = dn * (a2 + e2) + loadF(b2, cb + 2, f32);
        v3 = dn * (a3 + e3) + loadF(b2, cb + 3, f32);
    }
    float mx = fmaxf(fmaxf(v0, v1), fmaxf(v2, v3));
#pragma unroll
    for (int off = 8; off; off >>= 1) mx = fmaxf(mx, __shfl_xor(mx, off, 16));
    float ev = act ? expf(v0 - mx) + expf(v1 - mx) + expf(v2 - mx) + expf(v3 - mx) : 0.f;
#pragma unroll
    for (int off = 8; off; off >>= 1) ev += __shfl_xor(ev, off, 16);
    float lg = logf(ev);
    if (act) {
        float r0 = v0 - mx - lg, r1 = v1 - mx - lg;
        float r2 = v2 - mx - lg, r3 = v3 - mx - lg;
        if (f32) {
            *(float4*)((float*)out + (size_t)n * OUTD + cb) = make_float4(r0, r1, r2, r3);
        } else {
            ((uint2*)out)[(size_t)n * 10 + l16] = make_uint2(pack2bf(r0, r1), pack2bf(r2, r3));
        }
    }
}

extern "C" void kernel_launch(void* const* d_in, const int* in_sizes, int n_in,
                              void* d_out, int out_size, void* d_ws, size_t ws_size,
                              hipStream_t stream) {
    const void* x  = d_in[0];
    const int*  ei = (const int*)d_in[1];
    const void* W1 = d_in[2];
    const void* b1 = d_in[3];
    const void* W2 = d_in[4];
    const void* b2 = d_in[5];

    // ws layout (4-byte words):
    // flags[16] | dinv[50048] | cnt[50048] | row_start[50048] | partial[256] |
    // pp[256] | rank[800000] | csr16 ushort[800000] | h1' bf16 [NNP*64] |
    // h2' bf16 [NNP*40]   (~15.8 MB)
    float* ws        = (float*)d_ws;
    int*   flags     = (int*)ws;
    float* dinv      = ws + 16;
    int*   cnt       = (int*)(dinv + 50048);
    int*   row_start = cnt + 50048;
    int*   partial   = row_start + 50048;
    int*   pp        = partial + 256;
    int*   rank      = pp + 256;
    unsigned short* csr16 = (unsigned short*)(rank + NE);
    unsigned short* h1u   = csr16 + NE;
    unsigned short* h2u   = h1u + (size_t)NNP * HID;
    unsigned* h2pad = (unsigned*)(h2u + (size_t)ZR * OUTD);   // 20 dwords

    k_zero  <<<(NN + 255) / 256, 256, 0, stream>>>((const unsigned*)x, ei, flags, cnt, h2pad);
    k_hist  <<<(NE + 255) / 256, 256, 0, stream>>>(ei, flags, cnt, rank);
    k_scan1 <<<NC, 256, 0, stream>>>(cnt, row_start, partial, dinv);
    k_scan2p<<<1, 256, 0, stream>>>(partial, pp);
    k_fill  <<<NCH * 8, 256, 0, stream>>>(ei, flags, row_start, pp, rank, csr16);
    k_gemm1 <<<NNP / 64, 256, 0, stream>>>(x, W1, dinv, flags, h1u);
    k_gather1f<<<NN / 16, 256, 0, stream>>>((const uint2*)h1u, dinv, row_start, pp, cnt, csr16,
                                            W2, b1, flags, h2u);
    k_gather2<<<NN / 16, 256, 0, stream>>>((const uint2*)h2u, dinv, row_start, pp, cnt, csr16,
                                           b2, flags, d_out);
}